// Round 3
// baseline (881.562 us; speedup 1.0000x reference)
//
#include <hip/hip_runtime.h>

// TemporalGAT: LSTM(T=64,H=128) -> ReLU -> GCNConv -> ReLU -> GATConv(3x64) -> mean
// Round 17: software-pipeline the LSTM cg-groups at depth 2. Per body:
// issue MFMA(cg+1) into the alternate accumulator BEFORE phase4(cg), so the
// matrix pipe (~2100 cyc/step) hides under the phase-4 VALU chain (~5800
// cyc/step) instead of adding to it. Palindrome cg order (even t: 0..7,
// odd t: 7..0) keeps the single-buffered A-frag/bias prefetch at distance-1
// across the t boundary (last-used == first-needed). Fully unrolled bodies
// give compile-time cg everywhere -> cst[32] lives in registers (the r16
// VGPR=96 reading says runtime-indexed cst was in scratch). x[t+1]
// prefetched one step early (min-guarded at t=63).

#define N_NODES 20000
#define T_STEPS 64
#define N_EDGES 640000
#define HDIM    128
#define JOUT    192   // HEADS*OUT = 3*64
#define NEG_SLOPE 0.2f
#define NBW     16    // nodes per wave
#define WAVES   5
#define NBB     (NBW * WAVES)   // 80 nodes per block
#define LDS_W     131072                  // packed Whh fp16
#define LDS_BW    4096                    // (bias, wih) float2[512]
#define LDS_SCR   (WAVES * 4096)          // per-wave h scratch
#define LDS_TOTAL (LDS_W + LDS_BW + LDS_SCR)   // 155648

#define L2E  1.4426950408889634f
#define K2E  2.8853900817779268f   // 2*log2(e)

typedef _Float16 half8 __attribute__((ext_vector_type(8)));
typedef _Float16 half4v __attribute__((ext_vector_type(4)));
typedef float floatx4 __attribute__((ext_vector_type(4)));

__device__ __forceinline__ float lrelu(float x) { return x > 0.f ? x : NEG_SLOPE * x; }

// ---------------------------------------------------------------------------
// Pre-pack Whh (fp32 [512][128]) into fp16 MFMA A-fragment order, PRE-SCALED
// into the exp2 domain: rows of gates i,f,o scaled by log2e, g-gate rows by
// 2*log2e (so exp(2*g) becomes exp2(g')).
__global__ void pack_whh_kernel(const float* __restrict__ Whh,
                                _Float16* __restrict__ Wpack)
{
  int i = blockIdx.x * 256 + threadIdx.x;   // 0..8191
  int tile = i >> 6, lane = i & 63;
  int nt = tile >> 2, kt = tile & 3;
  int row = nt * 16 + (lane & 15);
  int c0  = kt * 32 + (lane >> 4) * 8;
  const float sc = ((row >> 7) == 2) ? K2E : L2E;
  half8 v;
  #pragma unroll
  for (int j = 0; j < 8; ++j)
    v[j] = (_Float16)(Whh[row * 128 + c0 + j] * sc);
  *(half8*)&Wpack[(size_t)i * 8] = v;
}

// ---------------------------------------------------------------------------
// Pipelined step building blocks (macros so every cg index is a literal).
#define PF_CG(cg) do {                                                        \
  _Pragma("unroll") for (int kt_ = 0; kt_ < 4; ++kt_)                         \
    _Pragma("unroll") for (int g_ = 0; g_ < 4; ++g_)                          \
      Afr[kt_ * 4 + g_] =                                                     \
        *(const half8*)&Wl[(size_t)(((g_ * 8 + (cg)) * 4 + kt_) * 64 + ln) * 8]; \
  _Pragma("unroll") for (int g_ = 0; g_ < 4; ++g_) {                          \
    const int b_ = g_ * 128 + (cg) * 16 + quad * 4;                           \
    P0[g_] = *(const float4*)&bw[b_];                                         \
    P1[g_] = *(const float4*)&bw[b_ + 2];                                     \
  }                                                                           \
} while (0)

#define INIT_MFMA(acc) do {                                                   \
  _Pragma("unroll") for (int g_ = 0; g_ < 4; ++g_) {                          \
    acc[g_][0] = P0[g_].x + xv * P0[g_].y;                                    \
    acc[g_][1] = P0[g_].z + xv * P0[g_].w;                                    \
    acc[g_][2] = P1[g_].x + xv * P1[g_].y;                                    \
    acc[g_][3] = P1[g_].z + xv * P1[g_].w;                                    \
  }                                                                           \
  _Pragma("unroll") for (int kt_ = 0; kt_ < 4; ++kt_)                         \
    _Pragma("unroll") for (int g_ = 0; g_ < 4; ++g_)                          \
      acc[g_] = __builtin_amdgcn_mfma_f32_16x16x32_f16(                       \
          Afr[kt_ * 4 + g_], Bf[kt_], acc[g_], 0, 0, 0);                      \
} while (0)

#define PHASE4(cg, acc) do {                                                  \
  half4v hpack;                                                               \
  _Pragma("unroll") for (int r_ = 0; r_ < 4; ++r_) {                          \
    const float Be = __builtin_amdgcn_exp2f(-acc[0][r_]);                     \
    const float Ae = __builtin_amdgcn_exp2f(-acc[1][r_]);                     \
    const float De = __builtin_amdgcn_exp2f(acc[2][r_]);                      \
    const float Ee = __builtin_amdgcn_exp2f(-acc[3][r_]);                     \
    const float Ap = Ae + 1.f;                                                \
    const float Bp = Be + 1.f;                                                \
    const float Dp = De + 1.f;                                                \
    const float Nn = cst[(cg) * 4 + r_] * Bp * Dp + Ap * (De - 1.f);          \
    const float cv = Nn * __builtin_amdgcn_rcpf(Ap * Bp * Dp);                \
    cst[(cg) * 4 + r_] = cv;                                                  \
    const float cvc = fminf(fmaxf(cv, -10.f), 10.f);                          \
    const float Fe = __builtin_amdgcn_exp2f(K2E * cvc);                       \
    hpack[r_] = (_Float16)((Fe - 1.f) *                                       \
                __builtin_amdgcn_rcpf((Ee + 1.f) * (Fe + 1.f)));              \
  }                                                                           \
  const int lp_ = nl + 16 * (2 * ((cg) & 1) + wq_hi);                         \
  *(half4v*)&myscr[((cg) >> 1) * 512 + lp_ * 8 + j0] = hpack;                 \
} while (0)

#define SB __builtin_amdgcn_sched_barrier(0)

// One LSTM step, cg order O0..O7 (palindrome between steps). Pipeline:
// pos j's MFMAs issue one body ahead of its phase4; prefetch in body i
// fetches operands for pos i+2 (body6 re-fetches O7 = next step's first).
#define LSTM_STEP(O0,O1,O2,O3,O4,O5,O6,O7) do {                               \
  half8 Bf[4];                                                                \
  _Pragma("unroll") for (int kt_ = 0; kt_ < 4; ++kt_)                         \
    Bf[kt_] = *(const half8*)&myscr[kt_ * 512 + ln * 8];                      \
  floatx4 accA[4], accB[4];                                                   \
  INIT_MFMA(accA);  PF_CG(O1); SB;                /* pos0 = O0 */             \
  INIT_MFMA(accB);  PF_CG(O2); SB; PHASE4(O0, accA);                          \
  INIT_MFMA(accA);  PF_CG(O3); SB; PHASE4(O1, accB);                          \
  INIT_MFMA(accB);  PF_CG(O4); SB; PHASE4(O2, accA);                          \
  INIT_MFMA(accA);  PF_CG(O5); SB; PHASE4(O3, accB);                          \
  INIT_MFMA(accB);  PF_CG(O6); SB; PHASE4(O4, accA);                          \
  INIT_MFMA(accA);  PF_CG(O7); SB; PHASE4(O5, accB);                          \
  INIT_MFMA(accB);  PF_CG(O7); SB; PHASE4(O6, accA);  /* pf next step's O0 */ \
  PHASE4(O7, accB);                                                           \
} while (0)

// ---------------------------------------------------------------------------
// Barrier-free LSTM. Block = 320 threads (5 waves), 80 nodes. Wave w owns
// nodes n0+w*16..+15; 128 MFMAs/step vs full 512-row gate matrix.
__global__ __attribute__((amdgpu_flat_work_group_size(320, 320),
                          amdgpu_waves_per_eu(1, 2)))
void lstm_stream_kernel(
    const float* __restrict__ xfeat, const _Float16* __restrict__ Wpack,
    const float* __restrict__ Wih, const float* __restrict__ bih,
    const float* __restrict__ bhh, float* __restrict__ x1)
{
  extern __shared__ char dynlds[];
  _Float16* Wl  = (_Float16*)dynlds;                    // [128 tiles][64 lanes][8]
  float2*   bw  = (float2*)(dynlds + LDS_W);            // [512] (bias, wih) pre-scaled
  _Float16* scr = (_Float16*)(dynlds + LDS_W + LDS_BW); // [5][2048]

  const int tid  = threadIdx.x;   // 0..319
  const int w    = tid >> 6;      // wave 0..4
  const int ln   = tid & 63;
  const int nl   = ln & 15;       // node within wave
  const int quad = ln >> 4;
  const int n0   = blockIdx.x * NBB + w * NBW;

  // stage packed Whh -> LDS (coalesced float4)
  {
    const float4* src = (const float4*)Wpack;
    float4* dst = (float4*)Wl;
    for (int i = tid; i < LDS_W / 16; i += 320) dst[i] = src[i];
  }
  for (int i = tid; i < 512; i += 320) {
    const float sc = ((i >> 7) == 2) ? K2E : L2E;
    bw[i] = make_float2((bih[i] + bhh[i]) * sc, Wih[i] * sc);
  }
  {
    float4* z = (float4*)scr;
    for (int i = tid; i < LDS_SCR / 16; i += 320)
      z[i] = make_float4(0.f, 0.f, 0.f, 0.f);
  }
  __syncthreads();   // the ONLY block barrier

  _Float16* myscr = scr + w * 2048;
  const float* xrow = xfeat + (size_t)(n0 + nl) * T_STEPS;

  float cst[32];
  #pragma unroll
  for (int i = 0; i < 32; ++i) cst[i] = 0.f;

  const int wq_hi = quad >> 1;
  const int j0    = (quad & 1) * 4;

  // prologue: prefetch A-fragments + (bias,wih) pairs for cg=0, and x[0]
  half8 Afr[16];
  float4 P0[4], P1[4];
  PF_CG(0);
  float xv = xrow[0];

  #pragma unroll 1
  for (int t = 0; t < T_STEPS; t += 2) {
    const float xn1 = xrow[t + 1];
    LSTM_STEP(0, 1, 2, 3, 4, 5, 6, 7);
    xv = xn1;
    const float xn2 = xrow[(t + 2 <= 63) ? (t + 2) : 63];
    LSTM_STEP(7, 6, 5, 4, 3, 2, 1, 0);
    xv = xn2;
  }

  // epilogue: final h sits in scratch in B-frag order -> x1 = relu(h)
  #pragma unroll
  for (int kt = 0; kt < 4; ++kt) {
    const half8 hf = *(const half8*)&myscr[kt * 512 + ln * 8];
    float* dst = x1 + (size_t)(n0 + nl) * HDIM + kt * 32 + quad * 8;
    float4 o0, o1;
    o0.x = fmaxf((float)hf[0], 0.f); o0.y = fmaxf((float)hf[1], 0.f);
    o0.z = fmaxf((float)hf[2], 0.f); o0.w = fmaxf((float)hf[3], 0.f);
    o1.x = fmaxf((float)hf[4], 0.f); o1.y = fmaxf((float)hf[5], 0.f);
    o1.z = fmaxf((float)hf[6], 0.f); o1.w = fmaxf((float)hf[7], 0.f);
    *(float4*)dst = o0;
    *(float4*)(dst + 4) = o1;
  }
}

// ---------------------------------------------------------------------------
// Y[n][j] = sum_k X[n][k] * W[j][k].  32 nodes/block, W LDS-tiled in 64-row chunks.
template <int J>
__global__ __launch_bounds__(256) void gemm_xw(
    const float* __restrict__ X, const float* __restrict__ W, float* __restrict__ Y)
{
  __shared__ float Xs[32 * 132];
  __shared__ float Ws[64 * 132];
  const int tid = threadIdx.x;
  const int n0  = blockIdx.x * 32;
  for (int i = tid; i < 32 * 128; i += 256) {
    int nn = i >> 7, k = i & 127;
    Xs[nn * 132 + k] = X[(n0 + nn) * 128 + k];
  }
  const int nl = tid >> 3;
  const int jb = tid & 7;
  for (int c0 = 0; c0 < J; c0 += 64) {
    __syncthreads();
    for (int i = tid; i < 64 * 128; i += 256) {
      int r = i >> 7, k = i & 127;
      Ws[r * 132 + k] = W[(c0 + r) * 128 + k];
    }
    __syncthreads();
    float acc[8];
    #pragma unroll
    for (int m = 0; m < 8; ++m) acc[m] = 0.f;
    for (int k0 = 0; k0 < 128; k0 += 8) {
      float xr[8];
      #pragma unroll
      for (int r = 0; r < 8; ++r) xr[r] = Xs[nl * 132 + k0 + r];
      #pragma unroll
      for (int m = 0; m < 8; ++m) {
        const float* w = &Ws[(jb + (m << 3)) * 132 + k0];
        float a = acc[m];
        #pragma unroll
        for (int r = 0; r < 8; ++r) a += xr[r] * w[r];
        acc[m] = a;
      }
    }
    #pragma unroll
    for (int m = 0; m < 8; ++m)
      Y[(n0 + nl) * J + c0 + jb + (m << 3)] = acc[m];
  }
}

// ---------------------------------------------------------------------------
__global__ void zero_kernel(float* __restrict__ deg, int* __restrict__ cnt,
                            float* __restrict__ accum)
{
  int i = blockIdx.x * 256 + threadIdx.x;
  if (i < N_NODES) { deg[i] = 0.f; cnt[i] = 0; }
  if (i < JOUT) accum[i] = 0.f;
}

__global__ void count_kernel(const int* __restrict__ ei, const float* __restrict__ ew,
                             int* __restrict__ cnt, float* __restrict__ deg)
{
  int e = blockIdx.x * 256 + threadIdx.x;
  int c = ei[N_EDGES + e];
  atomicAdd(&cnt[c], 1);
  atomicAdd(&deg[c], ew[e]);
}

// shuffle-based exclusive scan: thread t owns elements [t*20, t*20+20).
__global__ __launch_bounds__(1024) void scan_kernel(
    const int* __restrict__ cnt, int* __restrict__ rowptr, int* __restrict__ cursor,
    const float* __restrict__ deg, float* __restrict__ dinv)
{
  const int tid  = threadIdx.x;
  const int lane = tid & 63;
  const int wv   = tid >> 6;        // 16 waves
  const int base = tid * 20;
  int vals[20];
  int sum = 0;
  if (tid < 1000) {
    #pragma unroll
    for (int j = 0; j < 20; ++j) { vals[j] = sum; sum += cnt[base + j]; }
  }
  int inc = sum;
  #pragma unroll
  for (int off = 1; off < 64; off <<= 1) {
    int t = __shfl_up(inc, off);
    if (lane >= off) inc += t;
  }
  __shared__ int wtot[16];
  __shared__ int wpre[16];
  if (lane == 63) wtot[wv] = inc;
  __syncthreads();
  if (tid == 0) {
    int s = 0;
    for (int i = 0; i < 16; ++i) { wpre[i] = s; s += wtot[i]; }
    rowptr[N_NODES] = s;
  }
  __syncthreads();
  if (tid < 1000) {
    int off = wpre[wv] + (inc - sum);
    #pragma unroll
    for (int j = 0; j < 20; ++j) {
      int v = off + vals[j];
      rowptr[base + j] = v;
      cursor[base + j] = v;
    }
  }
  for (int i = tid; i < N_NODES; i += 1024)
    dinv[i] = rsqrtf(deg[i] + 1.0f);   // +1 = self-loop weight
}

__global__ void fill_kernel(const int* __restrict__ ei, const float* __restrict__ ew,
                            const float* __restrict__ dinv, int* __restrict__ cursor,
                            int* __restrict__ esrc, float* __restrict__ ewn)
{
  int e = blockIdx.x * 256 + threadIdx.x;
  int r = ei[e];
  int c = ei[N_EDGES + e];
  int p = atomicAdd(&cursor[c], 1);
  esrc[p] = r;
  ewn[p]  = ew[e] * dinv[r];   // pre-scale by dinv[row]
}

// ---------------------------------------------------------------------------
// GCN aggregation: one wave per destination node; 64-edge tiles staged in LDS,
// broadcast loop unrolled x4. x2 = relu(agg + b).
__global__ __launch_bounds__(256) void gcn_agg_kernel(
    const float* __restrict__ y, const float* __restrict__ dinv,
    const int* __restrict__ rowptr, const int* __restrict__ esrc,
    const float* __restrict__ ewn, const float* __restrict__ gcn_b,
    float* __restrict__ x2)
{
  __shared__ float2 stg[4][64];
  const int lane = threadIdx.x & 63;
  const int wv = threadIdx.x >> 6;
  const int c = blockIdx.x * 4 + wv;
  const float dc = dinv[c];
  const float2* y2 = (const float2*)y;
  float2 yc = y2[c * 64 + lane];
  float ax = yc.x * dc * dc, ay = yc.y * dc * dc;   // self-loop term
  const int e0 = rowptr[c], e1 = rowptr[c + 1];
  for (int tb = e0; tb < e1; tb += 64) {
    const int cnt = min(64, e1 - tb);
    const int k = tb + lane;
    if (k < e1) stg[wv][lane] = make_float2(__int_as_float(esrc[k]), ewn[k] * dc);
    __builtin_amdgcn_wave_barrier();
    int i = 0;
    for (; i + 4 <= cnt; i += 4) {
      float2 p0 = stg[wv][i],     p1 = stg[wv][i + 1];
      float2 p2 = stg[wv][i + 2], p3 = stg[wv][i + 3];
      const float2 a0 = y2[(size_t)__float_as_int(p0.x) * 64 + lane];
      const float2 a1 = y2[(size_t)__float_as_int(p1.x) * 64 + lane];
      const float2 a2 = y2[(size_t)__float_as_int(p2.x) * 64 + lane];
      const float2 a3 = y2[(size_t)__float_as_int(p3.x) * 64 + lane];
      ax += a0.x * p0.y + a1.x * p1.y + a2.x * p2.y + a3.x * p3.y;
      ay += a0.y * p0.y + a1.y * p1.y + a2.y * p2.y + a3.y * p3.y;
    }
    for (; i < cnt; ++i) {
      float2 p0 = stg[wv][i];
      const float2 a0 = y2[(size_t)__float_as_int(p0.x) * 64 + lane];
      ax += a0.x * p0.y; ay += a0.y * p0.y;
    }
    __builtin_amdgcn_wave_barrier();
  }
  int j0 = lane * 2;
  x2[c * 128 + j0]     = fmaxf(ax + gcn_b[j0], 0.f);
  x2[c * 128 + j0 + 1] = fmaxf(ay + gcn_b[j0 + 1], 0.f);
}

// ---------------------------------------------------------------------------
// Per-node attention logits: a_src/a_dst [N][4] (padded float4)
__global__ __launch_bounds__(256) void gat_att_kernel(
    const float* __restrict__ xh, const float* __restrict__ att_src,
    const float* __restrict__ att_dst, float4* __restrict__ asrc,
    float4* __restrict__ adst)
{
  const int lane = threadIdx.x & 63;
  const int nd = blockIdx.x * 4 + (threadIdx.x >> 6);
  float s[3], d[3];
  #pragma unroll
  for (int h = 0; h < 3; ++h) {
    float xv = xh[nd * JOUT + h * 64 + lane];
    s[h] = xv * att_src[h * 64 + lane];
    d[h] = xv * att_dst[h * 64 + lane];
  }
  #pragma unroll
  for (int off = 1; off < 64; off <<= 1) {
    #pragma unroll
    for (int h = 0; h < 3; ++h) {
      s[h] += __shfl_xor(s[h], off);
      d[h] += __shfl_xor(d[h], off);
    }
  }
  if (lane == 0) {
    asrc[nd] = make_float4(s[0], s[1], s[2], 0.f);
    adst[nd] = make_float4(d[0], d[1], d[2], 0.f);
  }
}

// GAT: softmax over incoming edges (incl self-loop) + weighted agg.
// One wave per node; first-tile alpha cached in regs; 64-edge LDS-staged tiles.
__global__ __launch_bounds__(256) void gat_agg_kernel(
    const float* __restrict__ xh, const float4* __restrict__ asrc,
    const float4* __restrict__ adst, const int* __restrict__ rowptr,
    const int* __restrict__ esrc, float* __restrict__ accum)
{
  __shared__ float4 cstg[4][64];
  const int lane = threadIdx.x & 63;
  const int wv = threadIdx.x >> 6;
  const int c = blockIdx.x * 4 + wv;
  const int e0 = rowptr[c], e1 = rowptr[c + 1];
  float4 adc = adst[c];
  float4 asc = asrc[c];
  float self0 = lrelu(asc.x + adc.x);
  float self1 = lrelu(asc.y + adc.y);
  float self2 = lrelu(asc.z + adc.z);

  const bool has = (e0 + lane < e1);
  int s_first = 0;
  float v0 = -3.0e38f, v1 = -3.0e38f, v2 = -3.0e38f;
  if (has) {
    s_first = esrc[e0 + lane];
    float4 av = asrc[s_first];
    v0 = lrelu(av.x + adc.x);
    v1 = lrelu(av.y + adc.y);
    v2 = lrelu(av.z + adc.z);
  }
  float m0 = fmaxf(self0, v0), m1 = fmaxf(self1, v1), m2 = fmaxf(self2, v2);
  for (int k = e0 + 64 + lane; k < e1; k += 64) {
    float4 av = asrc[esrc[k]];
    m0 = fmaxf(m0, lrelu(av.x + adc.x));
    m1 = fmaxf(m1, lrelu(av.y + adc.y));
    m2 = fmaxf(m2, lrelu(av.z + adc.z));
  }
  #pragma unroll
  for (int off = 1; off < 64; off <<= 1) {
    m0 = fmaxf(m0, __shfl_xor(m0, off));
    m1 = fmaxf(m1, __shfl_xor(m1, off));
    m2 = fmaxf(m2, __shfl_xor(m2, off));
  }
  float ex0 = has ? __expf(v0 - m0) : 0.f;
  float ex1 = has ? __expf(v1 - m1) : 0.f;
  float ex2 = has ? __expf(v2 - m2) : 0.f;
  float d0 = ex0, d1 = ex1, d2 = ex2;
  for (int k = e0 + 64 + lane; k < e1; k += 64) {
    float4 av = asrc[esrc[k]];
    d0 += __expf(lrelu(av.x + adc.x) - m0);
    d1 += __expf(lrelu(av.y + adc.y) - m1);
    d2 += __expf(lrelu(av.z + adc.z) - m2);
  }
  #pragma unroll
  for (int off = 1; off < 64; off <<= 1) {
    d0 += __shfl_xor(d0, off);
    d1 += __shfl_xor(d1, off);
    d2 += __shfl_xor(d2, off);
  }
  float se0 = __expf(self0 - m0), se1 = __expf(self1 - m1), se2 = __expf(self2 - m2);
  d0 += se0; d1 += se1; d2 += se2;
  float iv0 = 1.f / d0, iv1 = 1.f / d1, iv2 = 1.f / d2;

  float o0 = se0 * iv0 * xh[c * JOUT + lane];
  float o1 = se1 * iv1 * xh[c * JOUT + 64 + lane];
  float o2 = se2 * iv2 * xh[c * JOUT + 128 + lane];

  for (int tb = e0; tb < e1; tb += 64) {
    const int cnt = min(64, e1 - tb);
    if (tb == e0) {
      if (has)
        cstg[wv][lane] = make_float4(__int_as_float(s_first),
                                     ex0 * iv0, ex1 * iv1, ex2 * iv2);
    } else {
      const int k = tb + lane;
      if (k < e1) {
        int s = esrc[k];
        float4 av = asrc[s];
        cstg[wv][lane] = make_float4(__int_as_float(s),
            __expf(lrelu(av.x + adc.x) - m0) * iv0,
            __expf(lrelu(av.y + adc.y) - m1) * iv1,
            __expf(lrelu(av.z + adc.z) - m2) * iv2);
      }
    }
    __builtin_amdgcn_wave_barrier();
    int i = 0;
    for (; i + 2 <= cnt; i += 2) {
      float4 q0 = cstg[wv][i], q1 = cstg[wv][i + 1];
      const float* r0 = xh + (size_t)__float_as_int(q0.x) * JOUT;
      const float* r1 = xh + (size_t)__float_as_int(q1.x) * JOUT;
      float a0 = r0[lane], b0 = r0[64 + lane], g0 = r0[128 + lane];
      float a1 = r1[lane], b1 = r1[64 + lane], g1 = r1[128 + lane];
      o0 += q0.y * a0 + q1.y * a1;
      o1 += q0.z * b0 + q1.z * b1;
      o2 += q0.w * g0 + q1.w * g1;
    }
    for (; i < cnt; ++i) {
      float4 q0 = cstg[wv][i];
      const float* r0 = xh + (size_t)__float_as_int(q0.x) * JOUT;
      o0 += q0.y * r0[lane];
      o1 += q0.z * r0[64 + lane];
      o2 += q0.w * r0[128 + lane];
    }
    __builtin_amdgcn_wave_barrier();
  }

  __shared__ float red[4][JOUT];
  red[wv][lane]       = o0;
  red[wv][64 + lane]  = o1;
  red[wv][128 + lane] = o2;
  __syncthreads();
  if (threadIdx.x < JOUT) {
    float sum = red[0][threadIdx.x] + red[1][threadIdx.x] +
                red[2][threadIdx.x] + red[3][threadIdx.x];
    atomicAdd(&accum[threadIdx.x], sum);
  }
}

__global__ void finalize_kernel(const float* __restrict__ accum,
                                const float* __restrict__ gat_b,
                                float* __restrict__ out)
{
  int j = threadIdx.x;
  if (j < JOUT) out[j] = accum[j] * (1.0f / N_NODES) + gat_b[j];
}

// ---------------------------------------------------------------------------
extern "C" void kernel_launch(void* const* d_in, const int* in_sizes, int n_in,
                              void* d_out, int out_size, void* d_ws, size_t ws_size,
                              hipStream_t stream)
{
  const float* xfeat = (const float*)d_in[0];
  const int*   eidx  = (const int*)d_in[1];
  const float* eattr = (const float*)d_in[2];
  const float* Wih   = (const float*)d_in[3];
  const float* Whh   = (const float*)d_in[4];
  const float* bihp  = (const float*)d_in[5];
  const float* bhhp  = (const float*)d_in[6];
  const float* gcnW  = (const float*)d_in[7];
  const float* gcnb  = (const float*)d_in[8];
  const float* gatW  = (const float*)d_in[9];
  const float* attS  = (const float*)d_in[10];
  const float* attD  = (const float*)d_in[11];
  const float* gatb  = (const float*)d_in[12];
  float* out = (float*)d_out;

  char* ws = (char*)d_ws;
  size_t off = 0;
  auto alloc = [&](size_t bytes) {
    char* p = ws + off;
    off += (bytes + 255) & ~size_t(255);
    return p;
  };
  float*     x1     = (float*)alloc((size_t)N_NODES * 128 * 4);
  float*     y      = (float*)alloc((size_t)N_NODES * 128 * 4);
  float*     x2     = (float*)alloc((size_t)N_NODES * 128 * 4);
  float*     xh     = (float*)alloc((size_t)N_NODES * 192 * 4);
  float4*    asrc   = (float4*)alloc((size_t)N_NODES * 16);
  float4*    adst   = (float4*)alloc((size_t)N_NODES * 16);
  float*     deg    = (float*)alloc((size_t)N_NODES * 4);
  float*     dinv   = (float*)alloc((size_t)N_NODES * 4);
  int*       cnt    = (int*)alloc((size_t)N_NODES * 4);
  int*       rowptr = (int*)alloc((size_t)(N_NODES + 1) * 4);
  int*       cursor = (int*)alloc((size_t)N_NODES * 4);
  int*       esrc   = (int*)alloc((size_t)N_EDGES * 4);
  float*     ewn    = (float*)alloc((size_t)N_EDGES * 4);
  float*     accum  = (float*)alloc(JOUT * 4);
  _Float16*  wpack  = (_Float16*)alloc(131072);

  // opt-in to >64KB dynamic LDS for the barrier-free LSTM (idempotent)
  hipFuncSetAttribute((const void*)lstm_stream_kernel,
                      hipFuncAttributeMaxDynamicSharedMemorySize, LDS_TOTAL);

  zero_kernel<<<(N_NODES + 255) / 256, 256, 0, stream>>>(deg, cnt, accum);
  pack_whh_kernel<<<32, 256, 0, stream>>>(Whh, wpack);
  lstm_stream_kernel<<<N_NODES / NBB, 320, LDS_TOTAL, stream>>>(
      xfeat, wpack, Wih, bihp, bhhp, x1);
  count_kernel<<<N_EDGES / 256, 256, 0, stream>>>(eidx, eattr, cnt, deg);
  scan_kernel<<<1, 1024, 0, stream>>>(cnt, rowptr, cursor, deg, dinv);
  fill_kernel<<<N_EDGES / 256, 256, 0, stream>>>(eidx, eattr, dinv, cursor, esrc, ewn);
  gemm_xw<128><<<N_NODES / 32, 256, 0, stream>>>(x1, gcnW, y);
  gcn_agg_kernel<<<N_NODES / 4, 256, 0, stream>>>(y, dinv, rowptr, esrc, ewn, gcnb, x2);
  gemm_xw<192><<<N_NODES / 32, 256, 0, stream>>>(x2, gatW, xh);
  gat_att_kernel<<<N_NODES / 4, 256, 0, stream>>>(xh, attS, attD, asrc, adst);
  gat_agg_kernel<<<N_NODES / 4, 256, 0, stream>>>(xh, asrc, adst, rowptr, esrc, accum);
  finalize_kernel<<<1, 256, 0, stream>>>(accum, gatb, out);
}

// Round 4
// 823.633 us; speedup vs baseline: 1.0703x; 1.0703x over previous
//
#include <hip/hip_runtime.h>

// TemporalGAT: LSTM(T=64,H=128) -> ReLU -> GCNConv -> ReLU -> GATConv(3x64) -> mean
// Round 18: r17 post-mortem showed VALUBusy fell (40.8->36.5) with flat
// duration -> the LSTM is LATENCY-bound at ~1.25 waves/SIMD (1 block/CU,
// LDS-capped by the 128KB Whh). Fix occupancy without touching LDS: split
// each 16-node group's gates across a WAVE PAIR (role 0: cg0-3, role 1:
// cg4-7). Block = 640 threads = 10 waves, same 155648B LDS, 250 blocks ->
// 2.5 waves/SIMD, per-wave serial work per step halves. The recurrence now
// crosses waves: two __syncthreads per step (bar1 after Bf reads, bar2 after
// h writes). Scratch write regions are disjoint per role (banks 0-1 / 2-3);
// both roles read all 4 banks. amdgpu_waves_per_eu(3) caps VGPR at ~168 so
// the 3,3,2,2 per-SIMD residency of 10 waves is launchable.

#define N_NODES 20000
#define T_STEPS 64
#define N_EDGES 640000
#define HDIM    128
#define JOUT    192   // HEADS*OUT = 3*64
#define NEG_SLOPE 0.2f
#define NBW     16    // nodes per group
#define NGRP    5
#define NBB     (NBW * NGRP)   // 80 nodes per block
#define BTHR    640            // 10 waves: 5 groups x 2 roles
#define LDS_W     131072                  // packed Whh fp16
#define LDS_BW    4096                    // (bias, wih) float2[512]
#define LDS_SCR   (NGRP * 4096)           // per-group h scratch
#define LDS_TOTAL (LDS_W + LDS_BW + LDS_SCR)   // 155648

#define L2E  1.4426950408889634f
#define K2E  2.8853900817779268f   // 2*log2(e)

typedef _Float16 half8 __attribute__((ext_vector_type(8)));
typedef _Float16 half4v __attribute__((ext_vector_type(4)));
typedef float floatx4 __attribute__((ext_vector_type(4)));

__device__ __forceinline__ float lrelu(float x) { return x > 0.f ? x : NEG_SLOPE * x; }

// ---------------------------------------------------------------------------
// Pre-pack Whh (fp32 [512][128]) into fp16 MFMA A-fragment order, PRE-SCALED
// into the exp2 domain: rows of gates i,f,o scaled by log2e, g-gate rows by
// 2*log2e (so exp(2*g) becomes exp2(g')).
__global__ void pack_whh_kernel(const float* __restrict__ Whh,
                                _Float16* __restrict__ Wpack)
{
  int i = blockIdx.x * 256 + threadIdx.x;   // 0..8191
  int tile = i >> 6, lane = i & 63;
  int nt = tile >> 2, kt = tile & 3;
  int row = nt * 16 + (lane & 15);
  int c0  = kt * 32 + (lane >> 4) * 8;
  const float sc = ((row >> 7) == 2) ? K2E : L2E;
  half8 v;
  #pragma unroll
  for (int j = 0; j < 8; ++j)
    v[j] = (_Float16)(Whh[row * 128 + c0 + j] * sc);
  *(half8*)&Wpack[(size_t)i * 8] = v;
}

// ---------------------------------------------------------------------------
// Building blocks. L is a LITERAL local cg index (0..3); actual cg = cgb + L
// (cgb = role*4, wave-uniform). cst indexed by literal L -> stays in regs.
#define PF_CG(L) do {                                                         \
  const int cg_ = cgb + (L);                                                  \
  _Pragma("unroll") for (int kt_ = 0; kt_ < 4; ++kt_)                         \
    _Pragma("unroll") for (int g_ = 0; g_ < 4; ++g_)                          \
      Afr[kt_ * 4 + g_] =                                                     \
        *(const half8*)&Wl[(size_t)(((g_ * 8 + cg_) * 4 + kt_) * 64 + ln) * 8]; \
  _Pragma("unroll") for (int g_ = 0; g_ < 4; ++g_) {                          \
    const int b_ = g_ * 128 + cg_ * 16 + quad * 4;                            \
    P0[g_] = *(const float4*)&bw[b_];                                         \
    P1[g_] = *(const float4*)&bw[b_ + 2];                                     \
  }                                                                           \
} while (0)

#define INIT_MFMA(acc) do {                                                   \
  _Pragma("unroll") for (int g_ = 0; g_ < 4; ++g_) {                          \
    acc[g_][0] = P0[g_].x + xv * P0[g_].y;                                    \
    acc[g_][1] = P0[g_].z + xv * P0[g_].w;                                    \
    acc[g_][2] = P1[g_].x + xv * P1[g_].y;                                    \
    acc[g_][3] = P1[g_].z + xv * P1[g_].w;                                    \
  }                                                                           \
  _Pragma("unroll") for (int kt_ = 0; kt_ < 4; ++kt_)                         \
    _Pragma("unroll") for (int g_ = 0; g_ < 4; ++g_)                          \
      acc[g_] = __builtin_amdgcn_mfma_f32_16x16x32_f16(                       \
          Afr[kt_ * 4 + g_], Bf[kt_], acc[g_], 0, 0, 0);                      \
} while (0)

#define PHASE4(L, acc) do {                                                   \
  const int cg_ = cgb + (L);                                                  \
  half4v hpack;                                                               \
  _Pragma("unroll") for (int r_ = 0; r_ < 4; ++r_) {                          \
    const float Be = __builtin_amdgcn_exp2f(-acc[0][r_]);                     \
    const float Ae = __builtin_amdgcn_exp2f(-acc[1][r_]);                     \
    const float De = __builtin_amdgcn_exp2f(acc[2][r_]);                      \
    const float Ee = __builtin_amdgcn_exp2f(-acc[3][r_]);                     \
    const float Ap = Ae + 1.f;                                                \
    const float Bp = Be + 1.f;                                                \
    const float Dp = De + 1.f;                                                \
    const float Nn = cst[(L) * 4 + r_] * Bp * Dp + Ap * (De - 1.f);           \
    const float cv = Nn * __builtin_amdgcn_rcpf(Ap * Bp * Dp);                \
    cst[(L) * 4 + r_] = cv;                                                   \
    const float cvc = fminf(fmaxf(cv, -10.f), 10.f);                          \
    const float Fe = __builtin_amdgcn_exp2f(K2E * cvc);                       \
    hpack[r_] = (_Float16)((Fe - 1.f) *                                       \
                __builtin_amdgcn_rcpf((Ee + 1.f) * (Fe + 1.f)));              \
  }                                                                           \
  const int lp_ = nl + 16 * (2 * (cg_ & 1) + wq_hi);                          \
  *(half4v*)&myscr[(cg_ >> 1) * 512 + lp_ * 8 + j0] = hpack;                  \
} while (0)

#define SB __builtin_amdgcn_sched_barrier(0)

// One LSTM step for one role (4 cg groups), depth-2 pipelined, palindrome
// order between steps. bar1 after all scratch reads (h-writes start in body
// 2); bar2 after all writes (next step's reads follow).
#define LSTM_STEP(O0,O1,O2,O3) do {                                           \
  half8 Bf[4];                                                                \
  _Pragma("unroll") for (int kt_ = 0; kt_ < 4; ++kt_)                         \
    Bf[kt_] = *(const half8*)&myscr[kt_ * 512 + ln * 8];                      \
  floatx4 accA[4], accB[4];                                                   \
  INIT_MFMA(accA);  PF_CG(O1);                                                \
  __syncthreads();  /* bar1 */                                                \
  INIT_MFMA(accB);  PF_CG(O2); SB; PHASE4(O0, accA);                          \
  INIT_MFMA(accA);  PF_CG(O3); SB; PHASE4(O1, accB);                          \
  INIT_MFMA(accB);  PF_CG(O3); SB; PHASE4(O2, accA); /* pf next step's O0 */  \
  PHASE4(O3, accB);                                                           \
  __syncthreads();  /* bar2 */                                                \
} while (0)

// ---------------------------------------------------------------------------
// Wave-pair LSTM. Block = 640 threads (10 waves), 5 groups x 16 nodes.
// Group g's pair: wave 2g (role 0, cg0-3) + wave 2g+1 (role 1, cg4-7).
__global__ __attribute__((amdgpu_flat_work_group_size(BTHR, BTHR),
                          amdgpu_waves_per_eu(3)))
void lstm_stream_kernel(
    const float* __restrict__ xfeat, const _Float16* __restrict__ Wpack,
    const float* __restrict__ Wih, const float* __restrict__ bih,
    const float* __restrict__ bhh, float* __restrict__ x1)
{
  extern __shared__ char dynlds[];
  _Float16* Wl  = (_Float16*)dynlds;                    // [128 tiles][64 lanes][8]
  float2*   bw  = (float2*)(dynlds + LDS_W);            // [512] (bias, wih) pre-scaled
  _Float16* scr = (_Float16*)(dynlds + LDS_W + LDS_BW); // [5][2048]

  const int tid  = threadIdx.x;   // 0..639
  const int wv   = tid >> 6;      // wave 0..9
  const int grp  = wv >> 1;       // node group 0..4
  const int role = wv & 1;        // 0: cg0-3, 1: cg4-7
  const int cgb  = role * 4;
  const int ln   = tid & 63;
  const int nl   = ln & 15;       // node within group
  const int quad = ln >> 4;
  const int n0   = blockIdx.x * NBB + grp * NBW;

  // stage packed Whh -> LDS (coalesced float4)
  {
    const float4* src = (const float4*)Wpack;
    float4* dst = (float4*)Wl;
    for (int i = tid; i < LDS_W / 16; i += BTHR) dst[i] = src[i];
  }
  for (int i = tid; i < 512; i += BTHR) {
    const float sc = ((i >> 7) == 2) ? K2E : L2E;
    bw[i] = make_float2((bih[i] + bhh[i]) * sc, Wih[i] * sc);
  }
  {
    float4* z = (float4*)scr;
    for (int i = tid; i < LDS_SCR / 16; i += BTHR)
      z[i] = make_float4(0.f, 0.f, 0.f, 0.f);
  }
  __syncthreads();

  _Float16* myscr = scr + grp * 2048;
  const float* xrow = xfeat + (size_t)(n0 + nl) * T_STEPS;

  float cst[16];
  #pragma unroll
  for (int i = 0; i < 16; ++i) cst[i] = 0.f;

  const int wq_hi = quad >> 1;
  const int j0    = (quad & 1) * 4;

  // prologue: prefetch A-fragments + (bias,wih) pairs for local cg 0, and x[0]
  half8 Afr[16];
  float4 P0[4], P1[4];
  PF_CG(0);
  float xv = xrow[0];

  #pragma unroll 1
  for (int t = 0; t < T_STEPS; t += 2) {
    const float xn1 = xrow[t + 1];
    LSTM_STEP(0, 1, 2, 3);
    xv = xn1;
    const float xn2 = xrow[(t + 2 <= 63) ? (t + 2) : 63];
    LSTM_STEP(3, 2, 1, 0);
    xv = xn2;
  }

  // epilogue: final h sits in scratch in B-frag order -> x1 = relu(h).
  // role 0 writes kt banks 0-1, role 1 banks 2-3.
  #pragma unroll
  for (int k = 0; k < 2; ++k) {
    const int kt = role * 2 + k;
    const half8 hf = *(const half8*)&myscr[kt * 512 + ln * 8];
    float* dst = x1 + (size_t)(n0 + nl) * HDIM + kt * 32 + quad * 8;
    float4 o0, o1;
    o0.x = fmaxf((float)hf[0], 0.f); o0.y = fmaxf((float)hf[1], 0.f);
    o0.z = fmaxf((float)hf[2], 0.f); o0.w = fmaxf((float)hf[3], 0.f);
    o1.x = fmaxf((float)hf[4], 0.f); o1.y = fmaxf((float)hf[5], 0.f);
    o1.z = fmaxf((float)hf[6], 0.f); o1.w = fmaxf((float)hf[7], 0.f);
    *(float4*)dst = o0;
    *(float4*)(dst + 4) = o1;
  }
}

// ---------------------------------------------------------------------------
// Y[n][j] = sum_k X[n][k] * W[j][k].  32 nodes/block, W LDS-tiled in 64-row chunks.
template <int J>
__global__ __launch_bounds__(256) void gemm_xw(
    const float* __restrict__ X, const float* __restrict__ W, float* __restrict__ Y)
{
  __shared__ float Xs[32 * 132];
  __shared__ float Ws[64 * 132];
  const int tid = threadIdx.x;
  const int n0  = blockIdx.x * 32;
  for (int i = tid; i < 32 * 128; i += 256) {
    int nn = i >> 7, k = i & 127;
    Xs[nn * 132 + k] = X[(n0 + nn) * 128 + k];
  }
  const int nl = tid >> 3;
  const int jb = tid & 7;
  for (int c0 = 0; c0 < J; c0 += 64) {
    __syncthreads();
    for (int i = tid; i < 64 * 128; i += 256) {
      int r = i >> 7, k = i & 127;
      Ws[r * 132 + k] = W[(c0 + r) * 128 + k];
    }
    __syncthreads();
    float acc[8];
    #pragma unroll
    for (int m = 0; m < 8; ++m) acc[m] = 0.f;
    for (int k0 = 0; k0 < 128; k0 += 8) {
      float xr[8];
      #pragma unroll
      for (int r = 0; r < 8; ++r) xr[r] = Xs[nl * 132 + k0 + r];
      #pragma unroll
      for (int m = 0; m < 8; ++m) {
        const float* w = &Ws[(jb + (m << 3)) * 132 + k0];
        float a = acc[m];
        #pragma unroll
        for (int r = 0; r < 8; ++r) a += xr[r] * w[r];
        acc[m] = a;
      }
    }
    #pragma unroll
    for (int m = 0; m < 8; ++m)
      Y[(n0 + nl) * J + c0 + jb + (m << 3)] = acc[m];
  }
}

// ---------------------------------------------------------------------------
__global__ void zero_kernel(float* __restrict__ deg, int* __restrict__ cnt,
                            float* __restrict__ accum)
{
  int i = blockIdx.x * 256 + threadIdx.x;
  if (i < N_NODES) { deg[i] = 0.f; cnt[i] = 0; }
  if (i < JOUT) accum[i] = 0.f;
}

__global__ void count_kernel(const int* __restrict__ ei, const float* __restrict__ ew,
                             int* __restrict__ cnt, float* __restrict__ deg)
{
  int e = blockIdx.x * 256 + threadIdx.x;
  int c = ei[N_EDGES + e];
  atomicAdd(&cnt[c], 1);
  atomicAdd(&deg[c], ew[e]);
}

// shuffle-based exclusive scan: thread t owns elements [t*20, t*20+20).
__global__ __launch_bounds__(1024) void scan_kernel(
    const int* __restrict__ cnt, int* __restrict__ rowptr, int* __restrict__ cursor,
    const float* __restrict__ deg, float* __restrict__ dinv)
{
  const int tid  = threadIdx.x;
  const int lane = tid & 63;
  const int wv   = tid >> 6;        // 16 waves
  const int base = tid * 20;
  int vals[20];
  int sum = 0;
  if (tid < 1000) {
    #pragma unroll
    for (int j = 0; j < 20; ++j) { vals[j] = sum; sum += cnt[base + j]; }
  }
  int inc = sum;
  #pragma unroll
  for (int off = 1; off < 64; off <<= 1) {
    int t = __shfl_up(inc, off);
    if (lane >= off) inc += t;
  }
  __shared__ int wtot[16];
  __shared__ int wpre[16];
  if (lane == 63) wtot[wv] = inc;
  __syncthreads();
  if (tid == 0) {
    int s = 0;
    for (int i = 0; i < 16; ++i) { wpre[i] = s; s += wtot[i]; }
    rowptr[N_NODES] = s;
  }
  __syncthreads();
  if (tid < 1000) {
    int off = wpre[wv] + (inc - sum);
    #pragma unroll
    for (int j = 0; j < 20; ++j) {
      int v = off + vals[j];
      rowptr[base + j] = v;
      cursor[base + j] = v;
    }
  }
  for (int i = tid; i < N_NODES; i += 1024)
    dinv[i] = rsqrtf(deg[i] + 1.0f);   // +1 = self-loop weight
}

__global__ void fill_kernel(const int* __restrict__ ei, const float* __restrict__ ew,
                            const float* __restrict__ dinv, int* __restrict__ cursor,
                            int* __restrict__ esrc, float* __restrict__ ewn)
{
  int e = blockIdx.x * 256 + threadIdx.x;
  int r = ei[e];
  int c = ei[N_EDGES + e];
  int p = atomicAdd(&cursor[c], 1);
  esrc[p] = r;
  ewn[p]  = ew[e] * dinv[r];   // pre-scale by dinv[row]
}

// ---------------------------------------------------------------------------
// GCN aggregation: one wave per destination node; 64-edge tiles staged in LDS,
// broadcast loop unrolled x4. x2 = relu(agg + b).
__global__ __launch_bounds__(256) void gcn_agg_kernel(
    const float* __restrict__ y, const float* __restrict__ dinv,
    const int* __restrict__ rowptr, const int* __restrict__ esrc,
    const float* __restrict__ ewn, const float* __restrict__ gcn_b,
    float* __restrict__ x2)
{
  __shared__ float2 stg[4][64];
  const int lane = threadIdx.x & 63;
  const int wv = threadIdx.x >> 6;
  const int c = blockIdx.x * 4 + wv;
  const float dc = dinv[c];
  const float2* y2 = (const float2*)y;
  float2 yc = y2[c * 64 + lane];
  float ax = yc.x * dc * dc, ay = yc.y * dc * dc;   // self-loop term
  const int e0 = rowptr[c], e1 = rowptr[c + 1];
  for (int tb = e0; tb < e1; tb += 64) {
    const int cnt = min(64, e1 - tb);
    const int k = tb + lane;
    if (k < e1) stg[wv][lane] = make_float2(__int_as_float(esrc[k]), ewn[k] * dc);
    __builtin_amdgcn_wave_barrier();
    int i = 0;
    for (; i + 4 <= cnt; i += 4) {
      float2 p0 = stg[wv][i],     p1 = stg[wv][i + 1];
      float2 p2 = stg[wv][i + 2], p3 = stg[wv][i + 3];
      const float2 a0 = y2[(size_t)__float_as_int(p0.x) * 64 + lane];
      const float2 a1 = y2[(size_t)__float_as_int(p1.x) * 64 + lane];
      const float2 a2 = y2[(size_t)__float_as_int(p2.x) * 64 + lane];
      const float2 a3 = y2[(size_t)__float_as_int(p3.x) * 64 + lane];
      ax += a0.x * p0.y + a1.x * p1.y + a2.x * p2.y + a3.x * p3.y;
      ay += a0.y * p0.y + a1.y * p1.y + a2.y * p2.y + a3.y * p3.y;
    }
    for (; i < cnt; ++i) {
      float2 p0 = stg[wv][i];
      const float2 a0 = y2[(size_t)__float_as_int(p0.x) * 64 + lane];
      ax += a0.x * p0.y; ay += a0.y * p0.y;
    }
    __builtin_amdgcn_wave_barrier();
  }
  int j0 = lane * 2;
  x2[c * 128 + j0]     = fmaxf(ax + gcn_b[j0], 0.f);
  x2[c * 128 + j0 + 1] = fmaxf(ay + gcn_b[j0 + 1], 0.f);
}

// ---------------------------------------------------------------------------
// Per-node attention logits: a_src/a_dst [N][4] (padded float4)
__global__ __launch_bounds__(256) void gat_att_kernel(
    const float* __restrict__ xh, const float* __restrict__ att_src,
    const float* __restrict__ att_dst, float4* __restrict__ asrc,
    float4* __restrict__ adst)
{
  const int lane = threadIdx.x & 63;
  const int nd = blockIdx.x * 4 + (threadIdx.x >> 6);
  float s[3], d[3];
  #pragma unroll
  for (int h = 0; h < 3; ++h) {
    float xv = xh[nd * JOUT + h * 64 + lane];
    s[h] = xv * att_src[h * 64 + lane];
    d[h] = xv * att_dst[h * 64 + lane];
  }
  #pragma unroll
  for (int off = 1; off < 64; off <<= 1) {
    #pragma unroll
    for (int h = 0; h < 3; ++h) {
      s[h] += __shfl_xor(s[h], off);
      d[h] += __shfl_xor(d[h], off);
    }
  }
  if (lane == 0) {
    asrc[nd] = make_float4(s[0], s[1], s[2], 0.f);
    adst[nd] = make_float4(d[0], d[1], d[2], 0.f);
  }
}

// GAT: softmax over incoming edges (incl self-loop) + weighted agg.
// One wave per node; first-tile alpha cached in regs; 64-edge LDS-staged tiles.
__global__ __launch_bounds__(256) void gat_agg_kernel(
    const float* __restrict__ xh, const float4* __restrict__ asrc,
    const float4* __restrict__ adst, const int* __restrict__ rowptr,
    const int* __restrict__ esrc, float* __restrict__ accum)
{
  __shared__ float4 cstg[4][64];
  const int lane = threadIdx.x & 63;
  const int wv = threadIdx.x >> 6;
  const int c = blockIdx.x * 4 + wv;
  const int e0 = rowptr[c], e1 = rowptr[c + 1];
  float4 adc = adst[c];
  float4 asc = asrc[c];
  float self0 = lrelu(asc.x + adc.x);
  float self1 = lrelu(asc.y + adc.y);
  float self2 = lrelu(asc.z + adc.z);

  const bool has = (e0 + lane < e1);
  int s_first = 0;
  float v0 = -3.0e38f, v1 = -3.0e38f, v2 = -3.0e38f;
  if (has) {
    s_first = esrc[e0 + lane];
    float4 av = asrc[s_first];
    v0 = lrelu(av.x + adc.x);
    v1 = lrelu(av.y + adc.y);
    v2 = lrelu(av.z + adc.z);
  }
  float m0 = fmaxf(self0, v0), m1 = fmaxf(self1, v1), m2 = fmaxf(self2, v2);
  for (int k = e0 + 64 + lane; k < e1; k += 64) {
    float4 av = asrc[esrc[k]];
    m0 = fmaxf(m0, lrelu(av.x + adc.x));
    m1 = fmaxf(m1, lrelu(av.y + adc.y));
    m2 = fmaxf(m2, lrelu(av.z + adc.z));
  }
  #pragma unroll
  for (int off = 1; off < 64; off <<= 1) {
    m0 = fmaxf(m0, __shfl_xor(m0, off));
    m1 = fmaxf(m1, __shfl_xor(m1, off));
    m2 = fmaxf(m2, __shfl_xor(m2, off));
  }
  float ex0 = has ? __expf(v0 - m0) : 0.f;
  float ex1 = has ? __expf(v1 - m1) : 0.f;
  float ex2 = has ? __expf(v2 - m2) : 0.f;
  float d0 = ex0, d1 = ex1, d2 = ex2;
  for (int k = e0 + 64 + lane; k < e1; k += 64) {
    float4 av = asrc[esrc[k]];
    d0 += __expf(lrelu(av.x + adc.x) - m0);
    d1 += __expf(lrelu(av.y + adc.y) - m1);
    d2 += __expf(lrelu(av.z + adc.z) - m2);
  }
  #pragma unroll
  for (int off = 1; off < 64; off <<= 1) {
    d0 += __shfl_xor(d0, off);
    d1 += __shfl_xor(d1, off);
    d2 += __shfl_xor(d2, off);
  }
  float se0 = __expf(self0 - m0), se1 = __expf(self1 - m1), se2 = __expf(self2 - m2);
  d0 += se0; d1 += se1; d2 += se2;
  float iv0 = 1.f / d0, iv1 = 1.f / d1, iv2 = 1.f / d2;

  float o0 = se0 * iv0 * xh[c * JOUT + lane];
  float o1 = se1 * iv1 * xh[c * JOUT + 64 + lane];
  float o2 = se2 * iv2 * xh[c * JOUT + 128 + lane];

  for (int tb = e0; tb < e1; tb += 64) {
    const int cnt = min(64, e1 - tb);
    if (tb == e0) {
      if (has)
        cstg[wv][lane] = make_float4(__int_as_float(s_first),
                                     ex0 * iv0, ex1 * iv1, ex2 * iv2);
    } else {
      const int k = tb + lane;
      if (k < e1) {
        int s = esrc[k];
        float4 av = asrc[s];
        cstg[wv][lane] = make_float4(__int_as_float(s),
            __expf(lrelu(av.x + adc.x) - m0) * iv0,
            __expf(lrelu(av.y + adc.y) - m1) * iv1,
            __expf(lrelu(av.z + adc.z) - m2) * iv2);
      }
    }
    __builtin_amdgcn_wave_barrier();
    int i = 0;
    for (; i + 2 <= cnt; i += 2) {
      float4 q0 = cstg[wv][i], q1 = cstg[wv][i + 1];
      const float* r0 = xh + (size_t)__float_as_int(q0.x) * JOUT;
      const float* r1 = xh + (size_t)__float_as_int(q1.x) * JOUT;
      float a0 = r0[lane], b0 = r0[64 + lane], g0 = r0[128 + lane];
      float a1 = r1[lane], b1 = r1[64 + lane], g1 = r1[128 + lane];
      o0 += q0.y * a0 + q1.y * a1;
      o1 += q0.z * b0 + q1.z * b1;
      o2 += q0.w * g0 + q1.w * g1;
    }
    for (; i < cnt; ++i) {
      float4 q0 = cstg[wv][i];
      const float* r0 = xh + (size_t)__float_as_int(q0.x) * JOUT;
      o0 += q0.y * r0[lane];
      o1 += q0.z * r0[64 + lane];
      o2 += q0.w * r0[128 + lane];
    }
    __builtin_amdgcn_wave_barrier();
  }

  __shared__ float red[4][JOUT];
  red[wv][lane]       = o0;
  red[wv][64 + lane]  = o1;
  red[wv][128 + lane] = o2;
  __syncthreads();
  if (threadIdx.x < JOUT) {
    float sum = red[0][threadIdx.x] + red[1][threadIdx.x] +
                red[2][threadIdx.x] + red[3][threadIdx.x];
    atomicAdd(&accum[threadIdx.x], sum);
  }
}

__global__ void finalize_kernel(const float* __restrict__ accum,
                                const float* __restrict__ gat_b,
                                float* __restrict__ out)
{
  int j = threadIdx.x;
  if (j < JOUT) out[j] = accum[j] * (1.0f / N_NODES) + gat_b[j];
}

// ---------------------------------------------------------------------------
extern "C" void kernel_launch(void* const* d_in, const int* in_sizes, int n_in,
                              void* d_out, int out_size, void* d_ws, size_t ws_size,
                              hipStream_t stream)
{
  const float* xfeat = (const float*)d_in[0];
  const int*   eidx  = (const int*)d_in[1];
  const float* eattr = (const float*)d_in[2];
  const float* Wih   = (const float*)d_in[3];
  const float* Whh   = (const float*)d_in[4];
  const float* bihp  = (const float*)d_in[5];
  const float* bhhp  = (const float*)d_in[6];
  const float* gcnW  = (const float*)d_in[7];
  const float* gcnb  = (const float*)d_in[8];
  const float* gatW  = (const float*)d_in[9];
  const float* attS  = (const float*)d_in[10];
  const float* attD  = (const float*)d_in[11];
  const float* gatb  = (const float*)d_in[12];
  float* out = (float*)d_out;

  char* ws = (char*)d_ws;
  size_t off = 0;
  auto alloc = [&](size_t bytes) {
    char* p = ws + off;
    off += (bytes + 255) & ~size_t(255);
    return p;
  };
  float*     x1     = (float*)alloc((size_t)N_NODES * 128 * 4);
  float*     y      = (float*)alloc((size_t)N_NODES * 128 * 4);
  float*     x2     = (float*)alloc((size_t)N_NODES * 128 * 4);
  float*     xh     = (float*)alloc((size_t)N_NODES * 192 * 4);
  float4*    asrc   = (float4*)alloc((size_t)N_NODES * 16);
  float4*    adst   = (float4*)alloc((size_t)N_NODES * 16);
  float*     deg    = (float*)alloc((size_t)N_NODES * 4);
  float*     dinv   = (float*)alloc((size_t)N_NODES * 4);
  int*       cnt    = (int*)alloc((size_t)N_NODES * 4);
  int*       rowptr = (int*)alloc((size_t)(N_NODES + 1) * 4);
  int*       cursor = (int*)alloc((size_t)N_NODES * 4);
  int*       esrc   = (int*)alloc((size_t)N_EDGES * 4);
  float*     ewn    = (float*)alloc((size_t)N_EDGES * 4);
  float*     accum  = (float*)alloc(JOUT * 4);
  _Float16*  wpack  = (_Float16*)alloc(131072);

  // opt-in to >64KB dynamic LDS for the wave-pair LSTM (idempotent)
  hipFuncSetAttribute((const void*)lstm_stream_kernel,
                      hipFuncAttributeMaxDynamicSharedMemorySize, LDS_TOTAL);

  zero_kernel<<<(N_NODES + 255) / 256, 256, 0, stream>>>(deg, cnt, accum);
  pack_whh_kernel<<<32, 256, 0, stream>>>(Whh, wpack);
  lstm_stream_kernel<<<N_NODES / NBB, BTHR, LDS_TOTAL, stream>>>(
      xfeat, wpack, Wih, bihp, bhhp, x1);
  count_kernel<<<N_EDGES / 256, 256, 0, stream>>>(eidx, eattr, cnt, deg);
  scan_kernel<<<1, 1024, 0, stream>>>(cnt, rowptr, cursor, deg, dinv);
  fill_kernel<<<N_EDGES / 256, 256, 0, stream>>>(eidx, eattr, dinv, cursor, esrc, ewn);
  gemm_xw<128><<<N_NODES / 32, 256, 0, stream>>>(x1, gcnW, y);
  gcn_agg_kernel<<<N_NODES / 4, 256, 0, stream>>>(y, dinv, rowptr, esrc, ewn, gcnb, x2);
  gemm_xw<192><<<N_NODES / 32, 256, 0, stream>>>(x2, gatW, xh);
  gat_att_kernel<<<N_NODES / 4, 256, 0, stream>>>(xh, attS, attD, asrc, adst);
  gat_agg_kernel<<<N_NODES / 4, 256, 0, stream>>>(xh, asrc, adst, rowptr, esrc, accum);
  finalize_kernel<<<1, 256, 0, stream>>>(accum, gatb, out);
}

// Round 5
// 819.797 us; speedup vs baseline: 1.0753x; 1.0047x over previous
//
#include <hip/hip_runtime.h>

// TemporalGAT: LSTM(T=64,H=128) -> ReLU -> GCNConv -> ReLU -> GATConv(3x64) -> mean
// Round 19: r18's wave-pair split raised occupancy (10.8->28%) but
// amdgpu_waves_per_eu(3) min-only let the allocator target ~6 waves/EU ->
// VGPR=84 vs ~150 live -> scratch spill (WRITE_SIZE 10MB->169MB/dispatch).
// Fix: (1) waves_per_eu(3,3) pins the allocator at the 512/3=170-VGPR
// budget that matches the LDS-capped occupancy; (2) drop the P0/P1 bias
// prefetch regs (-32 VGPRs): INIT reads (bias,wih) float4 pairs straight
// from LDS (read-only -> barrier-safe; 2.8 waves/SIMD hide the ds_read).
// Liveness ~150 < 170 -> no spill.

#define N_NODES 20000
#define T_STEPS 64
#define N_EDGES 640000
#define HDIM    128
#define JOUT    192   // HEADS*OUT = 3*64
#define NEG_SLOPE 0.2f
#define NBW     16    // nodes per group
#define NGRP    5
#define NBB     (NBW * NGRP)   // 80 nodes per block
#define BTHR    640            // 10 waves: 5 groups x 2 roles
#define LDS_W     131072                  // packed Whh fp16
#define LDS_BW    4096                    // (bias, wih) float2[512]
#define LDS_SCR   (NGRP * 4096)           // per-group h scratch
#define LDS_TOTAL (LDS_W + LDS_BW + LDS_SCR)   // 155648

#define L2E  1.4426950408889634f
#define K2E  2.8853900817779268f   // 2*log2(e)

typedef _Float16 half8 __attribute__((ext_vector_type(8)));
typedef _Float16 half4v __attribute__((ext_vector_type(4)));
typedef float floatx4 __attribute__((ext_vector_type(4)));

__device__ __forceinline__ float lrelu(float x) { return x > 0.f ? x : NEG_SLOPE * x; }

// ---------------------------------------------------------------------------
// Pre-pack Whh (fp32 [512][128]) into fp16 MFMA A-fragment order, PRE-SCALED
// into the exp2 domain: rows of gates i,f,o scaled by log2e, g-gate rows by
// 2*log2e (so exp(2*g) becomes exp2(g')).
__global__ void pack_whh_kernel(const float* __restrict__ Whh,
                                _Float16* __restrict__ Wpack)
{
  int i = blockIdx.x * 256 + threadIdx.x;   // 0..8191
  int tile = i >> 6, lane = i & 63;
  int nt = tile >> 2, kt = tile & 3;
  int row = nt * 16 + (lane & 15);
  int c0  = kt * 32 + (lane >> 4) * 8;
  const float sc = ((row >> 7) == 2) ? K2E : L2E;
  half8 v;
  #pragma unroll
  for (int j = 0; j < 8; ++j)
    v[j] = (_Float16)(Whh[row * 128 + c0 + j] * sc);
  *(half8*)&Wpack[(size_t)i * 8] = v;
}

// ---------------------------------------------------------------------------
// Building blocks. L is a LITERAL local cg index (0..3); actual cg = cgb + L
// (cgb = role*4, wave-uniform). cst indexed by literal L -> stays in regs.
#define PF_CG(L) do {                                                         \
  const int cg_ = cgb + (L);                                                  \
  _Pragma("unroll") for (int kt_ = 0; kt_ < 4; ++kt_)                         \
    _Pragma("unroll") for (int g_ = 0; g_ < 4; ++g_)                          \
      Afr[kt_ * 4 + g_] =                                                     \
        *(const half8*)&Wl[(size_t)(((g_ * 8 + cg_) * 4 + kt_) * 64 + ln) * 8]; \
} while (0)

// acc init reads (bias,wih) directly from LDS (no prefetch regs), then MFMAs.
#define INIT_MFMA(L, acc) do {                                                \
  const int cg_ = cgb + (L);                                                  \
  _Pragma("unroll") for (int g_ = 0; g_ < 4; ++g_) {                          \
    const int b_ = g_ * 128 + cg_ * 16 + quad * 4;                            \
    const float4 p0_ = *(const float4*)&bw[b_];                               \
    const float4 p1_ = *(const float4*)&bw[b_ + 2];                           \
    acc[g_][0] = p0_.x + xv * p0_.y;                                          \
    acc[g_][1] = p0_.z + xv * p0_.w;                                          \
    acc[g_][2] = p1_.x + xv * p1_.y;                                          \
    acc[g_][3] = p1_.z + xv * p1_.w;                                          \
  }                                                                           \
  _Pragma("unroll") for (int kt_ = 0; kt_ < 4; ++kt_)                         \
    _Pragma("unroll") for (int g_ = 0; g_ < 4; ++g_)                          \
      acc[g_] = __builtin_amdgcn_mfma_f32_16x16x32_f16(                       \
          Afr[kt_ * 4 + g_], Bf[kt_], acc[g_], 0, 0, 0);                      \
} while (0)

#define PHASE4(L, acc) do {                                                   \
  const int cg_ = cgb + (L);                                                  \
  half4v hpack;                                                               \
  _Pragma("unroll") for (int r_ = 0; r_ < 4; ++r_) {                          \
    const float Be = __builtin_amdgcn_exp2f(-acc[0][r_]);                     \
    const float Ae = __builtin_amdgcn_exp2f(-acc[1][r_]);                     \
    const float De = __builtin_amdgcn_exp2f(acc[2][r_]);                      \
    const float Ee = __builtin_amdgcn_exp2f(-acc[3][r_]);                     \
    const float Ap = Ae + 1.f;                                                \
    const float Bp = Be + 1.f;                                                \
    const float Dp = De + 1.f;                                                \
    const float Nn = cst[(L) * 4 + r_] * Bp * Dp + Ap * (De - 1.f);           \
    const float cv = Nn * __builtin_amdgcn_rcpf(Ap * Bp * Dp);                \
    cst[(L) * 4 + r_] = cv;                                                   \
    const float cvc = fminf(fmaxf(cv, -10.f), 10.f);                          \
    const float Fe = __builtin_amdgcn_exp2f(K2E * cvc);                       \
    hpack[r_] = (_Float16)((Fe - 1.f) *                                       \
                __builtin_amdgcn_rcpf((Ee + 1.f) * (Fe + 1.f)));              \
  }                                                                           \
  const int lp_ = nl + 16 * (2 * (cg_ & 1) + wq_hi);                          \
  *(half4v*)&myscr[(cg_ >> 1) * 512 + lp_ * 8 + j0] = hpack;                  \
} while (0)

#define SB __builtin_amdgcn_sched_barrier(0)

// One LSTM step for one role (4 cg groups), depth-2 pipelined, palindrome
// order between steps. bar1 after all scratch reads (h-writes start after
// it); bar2 after all writes (next step's reads follow).
#define LSTM_STEP(O0,O1,O2,O3) do {                                           \
  half8 Bf[4];                                                                \
  _Pragma("unroll") for (int kt_ = 0; kt_ < 4; ++kt_)                         \
    Bf[kt_] = *(const half8*)&myscr[kt_ * 512 + ln * 8];                      \
  floatx4 accA[4], accB[4];                                                   \
  INIT_MFMA(O0, accA);  PF_CG(O1);                                            \
  __syncthreads();  /* bar1 */                                                \
  INIT_MFMA(O1, accB);  PF_CG(O2); SB; PHASE4(O0, accA);                      \
  INIT_MFMA(O2, accA);  PF_CG(O3); SB; PHASE4(O1, accB);                      \
  INIT_MFMA(O3, accB);  PF_CG(O3); SB; PHASE4(O2, accA); /* pf next O0 */     \
  PHASE4(O3, accB);                                                           \
  __syncthreads();  /* bar2 */                                                \
} while (0)

// ---------------------------------------------------------------------------
// Wave-pair LSTM. Block = 640 threads (10 waves), 5 groups x 16 nodes.
// Group g's pair: wave 2g (role 0, cg0-3) + wave 2g+1 (role 1, cg4-7).
__global__ __attribute__((amdgpu_flat_work_group_size(BTHR, BTHR),
                          amdgpu_waves_per_eu(3, 3)))
void lstm_stream_kernel(
    const float* __restrict__ xfeat, const _Float16* __restrict__ Wpack,
    const float* __restrict__ Wih, const float* __restrict__ bih,
    const float* __restrict__ bhh, float* __restrict__ x1)
{
  extern __shared__ char dynlds[];
  _Float16* Wl  = (_Float16*)dynlds;                    // [128 tiles][64 lanes][8]
  float2*   bw  = (float2*)(dynlds + LDS_W);            // [512] (bias, wih) pre-scaled
  _Float16* scr = (_Float16*)(dynlds + LDS_W + LDS_BW); // [5][2048]

  const int tid  = threadIdx.x;   // 0..639
  const int wv   = tid >> 6;      // wave 0..9
  const int grp  = wv >> 1;       // node group 0..4
  const int role = wv & 1;        // 0: cg0-3, 1: cg4-7
  const int cgb  = role * 4;
  const int ln   = tid & 63;
  const int nl   = ln & 15;       // node within group
  const int quad = ln >> 4;
  const int n0   = blockIdx.x * NBB + grp * NBW;

  // stage packed Whh -> LDS (coalesced float4)
  {
    const float4* src = (const float4*)Wpack;
    float4* dst = (float4*)Wl;
    for (int i = tid; i < LDS_W / 16; i += BTHR) dst[i] = src[i];
  }
  for (int i = tid; i < 512; i += BTHR) {
    const float sc = ((i >> 7) == 2) ? K2E : L2E;
    bw[i] = make_float2((bih[i] + bhh[i]) * sc, Wih[i] * sc);
  }
  {
    float4* z = (float4*)scr;
    for (int i = tid; i < LDS_SCR / 16; i += BTHR)
      z[i] = make_float4(0.f, 0.f, 0.f, 0.f);
  }
  __syncthreads();

  _Float16* myscr = scr + grp * 2048;
  const float* xrow = xfeat + (size_t)(n0 + nl) * T_STEPS;

  float cst[16];
  #pragma unroll
  for (int i = 0; i < 16; ++i) cst[i] = 0.f;

  const int wq_hi = quad >> 1;
  const int j0    = (quad & 1) * 4;

  // prologue: prefetch A-fragments for local cg 0, and x[0]
  half8 Afr[16];
  PF_CG(0);
  float xv = xrow[0];

  #pragma unroll 1
  for (int t = 0; t < T_STEPS; t += 2) {
    const float xn1 = xrow[t + 1];
    LSTM_STEP(0, 1, 2, 3);
    xv = xn1;
    const float xn2 = xrow[(t + 2 <= 63) ? (t + 2) : 63];
    LSTM_STEP(3, 2, 1, 0);
    xv = xn2;
  }

  // epilogue: final h sits in scratch in B-frag order -> x1 = relu(h).
  // role 0 writes kt banks 0-1, role 1 banks 2-3.
  #pragma unroll
  for (int k = 0; k < 2; ++k) {
    const int kt = role * 2 + k;
    const half8 hf = *(const half8*)&myscr[kt * 512 + ln * 8];
    float* dst = x1 + (size_t)(n0 + nl) * HDIM + kt * 32 + quad * 8;
    float4 o0, o1;
    o0.x = fmaxf((float)hf[0], 0.f); o0.y = fmaxf((float)hf[1], 0.f);
    o0.z = fmaxf((float)hf[2], 0.f); o0.w = fmaxf((float)hf[3], 0.f);
    o1.x = fmaxf((float)hf[4], 0.f); o1.y = fmaxf((float)hf[5], 0.f);
    o1.z = fmaxf((float)hf[6], 0.f); o1.w = fmaxf((float)hf[7], 0.f);
    *(float4*)dst = o0;
    *(float4*)(dst + 4) = o1;
  }
}

// ---------------------------------------------------------------------------
// Y[n][j] = sum_k X[n][k] * W[j][k].  32 nodes/block, W LDS-tiled in 64-row chunks.
template <int J>
__global__ __launch_bounds__(256) void gemm_xw(
    const float* __restrict__ X, const float* __restrict__ W, float* __restrict__ Y)
{
  __shared__ float Xs[32 * 132];
  __shared__ float Ws[64 * 132];
  const int tid = threadIdx.x;
  const int n0  = blockIdx.x * 32;
  for (int i = tid; i < 32 * 128; i += 256) {
    int nn = i >> 7, k = i & 127;
    Xs[nn * 132 + k] = X[(n0 + nn) * 128 + k];
  }
  const int nl = tid >> 3;
  const int jb = tid & 7;
  for (int c0 = 0; c0 < J; c0 += 64) {
    __syncthreads();
    for (int i = tid; i < 64 * 128; i += 256) {
      int r = i >> 7, k = i & 127;
      Ws[r * 132 + k] = W[(c0 + r) * 128 + k];
    }
    __syncthreads();
    float acc[8];
    #pragma unroll
    for (int m = 0; m < 8; ++m) acc[m] = 0.f;
    for (int k0 = 0; k0 < 128; k0 += 8) {
      float xr[8];
      #pragma unroll
      for (int r = 0; r < 8; ++r) xr[r] = Xs[nl * 132 + k0 + r];
      #pragma unroll
      for (int m = 0; m < 8; ++m) {
        const float* w = &Ws[(jb + (m << 3)) * 132 + k0];
        float a = acc[m];
        #pragma unroll
        for (int r = 0; r < 8; ++r) a += xr[r] * w[r];
        acc[m] = a;
      }
    }
    #pragma unroll
    for (int m = 0; m < 8; ++m)
      Y[(n0 + nl) * J + c0 + jb + (m << 3)] = acc[m];
  }
}

// ---------------------------------------------------------------------------
__global__ void zero_kernel(float* __restrict__ deg, int* __restrict__ cnt,
                            float* __restrict__ accum)
{
  int i = blockIdx.x * 256 + threadIdx.x;
  if (i < N_NODES) { deg[i] = 0.f; cnt[i] = 0; }
  if (i < JOUT) accum[i] = 0.f;
}

__global__ void count_kernel(const int* __restrict__ ei, const float* __restrict__ ew,
                             int* __restrict__ cnt, float* __restrict__ deg)
{
  int e = blockIdx.x * 256 + threadIdx.x;
  int c = ei[N_EDGES + e];
  atomicAdd(&cnt[c], 1);
  atomicAdd(&deg[c], ew[e]);
}

// shuffle-based exclusive scan: thread t owns elements [t*20, t*20+20).
__global__ __launch_bounds__(1024) void scan_kernel(
    const int* __restrict__ cnt, int* __restrict__ rowptr, int* __restrict__ cursor,
    const float* __restrict__ deg, float* __restrict__ dinv)
{
  const int tid  = threadIdx.x;
  const int lane = tid & 63;
  const int wv   = tid >> 6;        // 16 waves
  const int base = tid * 20;
  int vals[20];
  int sum = 0;
  if (tid < 1000) {
    #pragma unroll
    for (int j = 0; j < 20; ++j) { vals[j] = sum; sum += cnt[base + j]; }
  }
  int inc = sum;
  #pragma unroll
  for (int off = 1; off < 64; off <<= 1) {
    int t = __shfl_up(inc, off);
    if (lane >= off) inc += t;
  }
  __shared__ int wtot[16];
  __shared__ int wpre[16];
  if (lane == 63) wtot[wv] = inc;
  __syncthreads();
  if (tid == 0) {
    int s = 0;
    for (int i = 0; i < 16; ++i) { wpre[i] = s; s += wtot[i]; }
    rowptr[N_NODES] = s;
  }
  __syncthreads();
  if (tid < 1000) {
    int off = wpre[wv] + (inc - sum);
    #pragma unroll
    for (int j = 0; j < 20; ++j) {
      int v = off + vals[j];
      rowptr[base + j] = v;
      cursor[base + j] = v;
    }
  }
  for (int i = tid; i < N_NODES; i += 1024)
    dinv[i] = rsqrtf(deg[i] + 1.0f);   // +1 = self-loop weight
}

__global__ void fill_kernel(const int* __restrict__ ei, const float* __restrict__ ew,
                            const float* __restrict__ dinv, int* __restrict__ cursor,
                            int* __restrict__ esrc, float* __restrict__ ewn)
{
  int e = blockIdx.x * 256 + threadIdx.x;
  int r = ei[e];
  int c = ei[N_EDGES + e];
  int p = atomicAdd(&cursor[c], 1);
  esrc[p] = r;
  ewn[p]  = ew[e] * dinv[r];   // pre-scale by dinv[row]
}

// ---------------------------------------------------------------------------
// GCN aggregation: one wave per destination node; 64-edge tiles staged in LDS,
// broadcast loop unrolled x4. x2 = relu(agg + b).
__global__ __launch_bounds__(256) void gcn_agg_kernel(
    const float* __restrict__ y, const float* __restrict__ dinv,
    const int* __restrict__ rowptr, const int* __restrict__ esrc,
    const float* __restrict__ ewn, const float* __restrict__ gcn_b,
    float* __restrict__ x2)
{
  __shared__ float2 stg[4][64];
  const int lane = threadIdx.x & 63;
  const int wv = threadIdx.x >> 6;
  const int c = blockIdx.x * 4 + wv;
  const float dc = dinv[c];
  const float2* y2 = (const float2*)y;
  float2 yc = y2[c * 64 + lane];
  float ax = yc.x * dc * dc, ay = yc.y * dc * dc;   // self-loop term
  const int e0 = rowptr[c], e1 = rowptr[c + 1];
  for (int tb = e0; tb < e1; tb += 64) {
    const int cnt = min(64, e1 - tb);
    const int k = tb + lane;
    if (k < e1) stg[wv][lane] = make_float2(__int_as_float(esrc[k]), ewn[k] * dc);
    __builtin_amdgcn_wave_barrier();
    int i = 0;
    for (; i + 4 <= cnt; i += 4) {
      float2 p0 = stg[wv][i],     p1 = stg[wv][i + 1];
      float2 p2 = stg[wv][i + 2], p3 = stg[wv][i + 3];
      const float2 a0 = y2[(size_t)__float_as_int(p0.x) * 64 + lane];
      const float2 a1 = y2[(size_t)__float_as_int(p1.x) * 64 + lane];
      const float2 a2 = y2[(size_t)__float_as_int(p2.x) * 64 + lane];
      const float2 a3 = y2[(size_t)__float_as_int(p3.x) * 64 + lane];
      ax += a0.x * p0.y + a1.x * p1.y + a2.x * p2.y + a3.x * p3.y;
      ay += a0.y * p0.y + a1.y * p1.y + a2.y * p2.y + a3.y * p3.y;
    }
    for (; i < cnt; ++i) {
      float2 p0 = stg[wv][i];
      const float2 a0 = y2[(size_t)__float_as_int(p0.x) * 64 + lane];
      ax += a0.x * p0.y; ay += a0.y * p0.y;
    }
    __builtin_amdgcn_wave_barrier();
  }
  int j0 = lane * 2;
  x2[c * 128 + j0]     = fmaxf(ax + gcn_b[j0], 0.f);
  x2[c * 128 + j0 + 1] = fmaxf(ay + gcn_b[j0 + 1], 0.f);
}

// ---------------------------------------------------------------------------
// Per-node attention logits: a_src/a_dst [N][4] (padded float4)
__global__ __launch_bounds__(256) void gat_att_kernel(
    const float* __restrict__ xh, const float* __restrict__ att_src,
    const float* __restrict__ att_dst, float4* __restrict__ asrc,
    float4* __restrict__ adst)
{
  const int lane = threadIdx.x & 63;
  const int nd = blockIdx.x * 4 + (threadIdx.x >> 6);
  float s[3], d[3];
  #pragma unroll
  for (int h = 0; h < 3; ++h) {
    float xv = xh[nd * JOUT + h * 64 + lane];
    s[h] = xv * att_src[h * 64 + lane];
    d[h] = xv * att_dst[h * 64 + lane];
  }
  #pragma unroll
  for (int off = 1; off < 64; off <<= 1) {
    #pragma unroll
    for (int h = 0; h < 3; ++h) {
      s[h] += __shfl_xor(s[h], off);
      d[h] += __shfl_xor(d[h], off);
    }
  }
  if (lane == 0) {
    asrc[nd] = make_float4(s[0], s[1], s[2], 0.f);
    adst[nd] = make_float4(d[0], d[1], d[2], 0.f);
  }
}

// GAT: softmax over incoming edges (incl self-loop) + weighted agg.
// One wave per node; first-tile alpha cached in regs; 64-edge LDS-staged tiles.
__global__ __launch_bounds__(256) void gat_agg_kernel(
    const float* __restrict__ xh, const float4* __restrict__ asrc,
    const float4* __restrict__ adst, const int* __restrict__ rowptr,
    const int* __restrict__ esrc, float* __restrict__ accum)
{
  __shared__ float4 cstg[4][64];
  const int lane = threadIdx.x & 63;
  const int wv = threadIdx.x >> 6;
  const int c = blockIdx.x * 4 + wv;
  const int e0 = rowptr[c], e1 = rowptr[c + 1];
  float4 adc = adst[c];
  float4 asc = asrc[c];
  float self0 = lrelu(asc.x + adc.x);
  float self1 = lrelu(asc.y + adc.y);
  float self2 = lrelu(asc.z + adc.z);

  const bool has = (e0 + lane < e1);
  int s_first = 0;
  float v0 = -3.0e38f, v1 = -3.0e38f, v2 = -3.0e38f;
  if (has) {
    s_first = esrc[e0 + lane];
    float4 av = asrc[s_first];
    v0 = lrelu(av.x + adc.x);
    v1 = lrelu(av.y + adc.y);
    v2 = lrelu(av.z + adc.z);
  }
  float m0 = fmaxf(self0, v0), m1 = fmaxf(self1, v1), m2 = fmaxf(self2, v2);
  for (int k = e0 + 64 + lane; k < e1; k += 64) {
    float4 av = asrc[esrc[k]];
    m0 = fmaxf(m0, lrelu(av.x + adc.x));
    m1 = fmaxf(m1, lrelu(av.y + adc.y));
    m2 = fmaxf(m2, lrelu(av.z + adc.z));
  }
  #pragma unroll
  for (int off = 1; off < 64; off <<= 1) {
    m0 = fmaxf(m0, __shfl_xor(m0, off));
    m1 = fmaxf(m1, __shfl_xor(m1, off));
    m2 = fmaxf(m2, __shfl_xor(m2, off));
  }
  float ex0 = has ? __expf(v0 - m0) : 0.f;
  float ex1 = has ? __expf(v1 - m1) : 0.f;
  float ex2 = has ? __expf(v2 - m2) : 0.f;
  float d0 = ex0, d1 = ex1, d2 = ex2;
  for (int k = e0 + 64 + lane; k < e1; k += 64) {
    float4 av = asrc[esrc[k]];
    d0 += __expf(lrelu(av.x + adc.x) - m0);
    d1 += __expf(lrelu(av.y + adc.y) - m1);
    d2 += __expf(lrelu(av.z + adc.z) - m2);
  }
  #pragma unroll
  for (int off = 1; off < 64; off <<= 1) {
    d0 += __shfl_xor(d0, off);
    d1 += __shfl_xor(d1, off);
    d2 += __shfl_xor(d2, off);
  }
  float se0 = __expf(self0 - m0), se1 = __expf(self1 - m1), se2 = __expf(self2 - m2);
  d0 += se0; d1 += se1; d2 += se2;
  float iv0 = 1.f / d0, iv1 = 1.f / d1, iv2 = 1.f / d2;

  float o0 = se0 * iv0 * xh[c * JOUT + lane];
  float o1 = se1 * iv1 * xh[c * JOUT + 64 + lane];
  float o2 = se2 * iv2 * xh[c * JOUT + 128 + lane];

  for (int tb = e0; tb < e1; tb += 64) {
    const int cnt = min(64, e1 - tb);
    if (tb == e0) {
      if (has)
        cstg[wv][lane] = make_float4(__int_as_float(s_first),
                                     ex0 * iv0, ex1 * iv1, ex2 * iv2);
    } else {
      const int k = tb + lane;
      if (k < e1) {
        int s = esrc[k];
        float4 av = asrc[s];
        cstg[wv][lane] = make_float4(__int_as_float(s),
            __expf(lrelu(av.x + adc.x) - m0) * iv0,
            __expf(lrelu(av.y + adc.y) - m1) * iv1,
            __expf(lrelu(av.z + adc.z) - m2) * iv2);
      }
    }
    __builtin_amdgcn_wave_barrier();
    int i = 0;
    for (; i + 2 <= cnt; i += 2) {
      float4 q0 = cstg[wv][i], q1 = cstg[wv][i + 1];
      const float* r0 = xh + (size_t)__float_as_int(q0.x) * JOUT;
      const float* r1 = xh + (size_t)__float_as_int(q1.x) * JOUT;
      float a0 = r0[lane], b0 = r0[64 + lane], g0 = r0[128 + lane];
      float a1 = r1[lane], b1 = r1[64 + lane], g1 = r1[128 + lane];
      o0 += q0.y * a0 + q1.y * a1;
      o1 += q0.z * b0 + q1.z * b1;
      o2 += q0.w * g0 + q1.w * g1;
    }
    for (; i < cnt; ++i) {
      float4 q0 = cstg[wv][i];
      const float* r0 = xh + (size_t)__float_as_int(q0.x) * JOUT;
      o0 += q0.y * r0[lane];
      o1 += q0.z * r0[64 + lane];
      o2 += q0.w * r0[128 + lane];
    }
    __builtin_amdgcn_wave_barrier();
  }

  __shared__ float red[4][JOUT];
  red[wv][lane]       = o0;
  red[wv][64 + lane]  = o1;
  red[wv][128 + lane] = o2;
  __syncthreads();
  if (threadIdx.x < JOUT) {
    float sum = red[0][threadIdx.x] + red[1][threadIdx.x] +
                red[2][threadIdx.x] + red[3][threadIdx.x];
    atomicAdd(&accum[threadIdx.x], sum);
  }
}

__global__ void finalize_kernel(const float* __restrict__ accum,
                                const float* __restrict__ gat_b,
                                float* __restrict__ out)
{
  int j = threadIdx.x;
  if (j < JOUT) out[j] = accum[j] * (1.0f / N_NODES) + gat_b[j];
}

// ---------------------------------------------------------------------------
extern "C" void kernel_launch(void* const* d_in, const int* in_sizes, int n_in,
                              void* d_out, int out_size, void* d_ws, size_t ws_size,
                              hipStream_t stream)
{
  const float* xfeat = (const float*)d_in[0];
  const int*   eidx  = (const int*)d_in[1];
  const float* eattr = (const float*)d_in[2];
  const float* Wih   = (const float*)d_in[3];
  const float* Whh   = (const float*)d_in[4];
  const float* bihp  = (const float*)d_in[5];
  const float* bhhp  = (const float*)d_in[6];
  const float* gcnW  = (const float*)d_in[7];
  const float* gcnb  = (const float*)d_in[8];
  const float* gatW  = (const float*)d_in[9];
  const float* attS  = (const float*)d_in[10];
  const float* attD  = (const float*)d_in[11];
  const float* gatb  = (const float*)d_in[12];
  float* out = (float*)d_out;

  char* ws = (char*)d_ws;
  size_t off = 0;
  auto alloc = [&](size_t bytes) {
    char* p = ws + off;
    off += (bytes + 255) & ~size_t(255);
    return p;
  };
  float*     x1     = (float*)alloc((size_t)N_NODES * 128 * 4);
  float*     y      = (float*)alloc((size_t)N_NODES * 128 * 4);
  float*     x2     = (float*)alloc((size_t)N_NODES * 128 * 4);
  float*     xh     = (float*)alloc((size_t)N_NODES * 192 * 4);
  float4*    asrc   = (float4*)alloc((size_t)N_NODES * 16);
  float4*    adst   = (float4*)alloc((size_t)N_NODES * 16);
  float*     deg    = (float*)alloc((size_t)N_NODES * 4);
  float*     dinv   = (float*)alloc((size_t)N_NODES * 4);
  int*       cnt    = (int*)alloc((size_t)N_NODES * 4);
  int*       rowptr = (int*)alloc((size_t)(N_NODES + 1) * 4);
  int*       cursor = (int*)alloc((size_t)N_NODES * 4);
  int*       esrc   = (int*)alloc((size_t)N_EDGES * 4);
  float*     ewn    = (float*)alloc((size_t)N_EDGES * 4);
  float*     accum  = (float*)alloc(JOUT * 4);
  _Float16*  wpack  = (_Float16*)alloc(131072);

  // opt-in to >64KB dynamic LDS for the wave-pair LSTM (idempotent)
  hipFuncSetAttribute((const void*)lstm_stream_kernel,
                      hipFuncAttributeMaxDynamicSharedMemorySize, LDS_TOTAL);

  zero_kernel<<<(N_NODES + 255) / 256, 256, 0, stream>>>(deg, cnt, accum);
  pack_whh_kernel<<<32, 256, 0, stream>>>(Whh, wpack);
  lstm_stream_kernel<<<N_NODES / NBB, BTHR, LDS_TOTAL, stream>>>(
      xfeat, wpack, Wih, bihp, bhhp, x1);
  count_kernel<<<N_EDGES / 256, 256, 0, stream>>>(eidx, eattr, cnt, deg);
  scan_kernel<<<1, 1024, 0, stream>>>(cnt, rowptr, cursor, deg, dinv);
  fill_kernel<<<N_EDGES / 256, 256, 0, stream>>>(eidx, eattr, dinv, cursor, esrc, ewn);
  gemm_xw<128><<<N_NODES / 32, 256, 0, stream>>>(x1, gcnW, y);
  gcn_agg_kernel<<<N_NODES / 4, 256, 0, stream>>>(y, dinv, rowptr, esrc, ewn, gcnb, x2);
  gemm_xw<192><<<N_NODES / 32, 256, 0, stream>>>(x2, gatW, xh);
  gat_att_kernel<<<N_NODES / 4, 256, 0, stream>>>(xh, attS, attD, asrc, adst);
  gat_agg_kernel<<<N_NODES / 4, 256, 0, stream>>>(xh, asrc, adst, rowptr, esrc, accum);
  finalize_kernel<<<1, 256, 0, stream>>>(accum, gatb, out);
}

// Round 6
// 798.260 us; speedup vs baseline: 1.1044x; 1.0270x over previous
//
#include <hip/hip_runtime.h>

// TemporalGAT: LSTM(T=64,H=128) -> ReLU -> GCNConv -> ReLU -> GATConv(3x64) -> mean
// Round 20: r19 showed waves_per_eu(3,3) does NOT raise the VGPR budget
// (stuck at 84 = ~6 waves/EU target; 10-wave WGs + invisible dynamic LDS
// make a 3/EU request unsatisfiable) -> the persistent Afr[16] (64 VGPRs,
// live across PHASE4) kept spilling (WRITE_SIZE 154MB). Fix: make liveness
// fit 84. Fold A-fragment loads INTO the MFMA sequence with two ping-pong
// 4-frag buffers (32 regs): LDA(kt0),LDA(kt1) pinned before prev-cg PHASE4
// (latency hidden under its VALU chain), then MFA/LDA interleave for
// kt2/kt3. Peak VGPR liveness ~80 (+acc in AGPRs). Depth-2 acc pipeline
// and wave-pair occupancy structure unchanged; palindrome order no longer
// needed (nothing persists across bodies).

#define N_NODES 20000
#define T_STEPS 64
#define N_EDGES 640000
#define HDIM    128
#define JOUT    192   // HEADS*OUT = 3*64
#define NEG_SLOPE 0.2f
#define NBW     16    // nodes per group
#define NGRP    5
#define NBB     (NBW * NGRP)   // 80 nodes per block
#define BTHR    640            // 10 waves: 5 groups x 2 roles
#define LDS_W     131072                  // packed Whh fp16
#define LDS_BW    4096                    // (bias, wih) float2[512]
#define LDS_SCR   (NGRP * 4096)           // per-group h scratch
#define LDS_TOTAL (LDS_W + LDS_BW + LDS_SCR)   // 155648

#define L2E  1.4426950408889634f
#define K2E  2.8853900817779268f   // 2*log2(e)

typedef _Float16 half8 __attribute__((ext_vector_type(8)));
typedef _Float16 half4v __attribute__((ext_vector_type(4)));
typedef float floatx4 __attribute__((ext_vector_type(4)));

__device__ __forceinline__ float lrelu(float x) { return x > 0.f ? x : NEG_SLOPE * x; }

// ---------------------------------------------------------------------------
// Pre-pack Whh (fp32 [512][128]) into fp16 MFMA A-fragment order, PRE-SCALED
// into the exp2 domain: rows of gates i,f,o scaled by log2e, g-gate rows by
// 2*log2e (so exp(2*g) becomes exp2(g')).
__global__ void pack_whh_kernel(const float* __restrict__ Whh,
                                _Float16* __restrict__ Wpack)
{
  int i = blockIdx.x * 256 + threadIdx.x;   // 0..8191
  int tile = i >> 6, lane = i & 63;
  int nt = tile >> 2, kt = tile & 3;
  int row = nt * 16 + (lane & 15);
  int c0  = kt * 32 + (lane >> 4) * 8;
  const float sc = ((row >> 7) == 2) ? K2E : L2E;
  half8 v;
  #pragma unroll
  for (int j = 0; j < 8; ++j)
    v[j] = (_Float16)(Whh[row * 128 + c0 + j] * sc);
  *(half8*)&Wpack[(size_t)i * 8] = v;
}

// ---------------------------------------------------------------------------
// Building blocks. L is a LITERAL local cg index (0..3); actual cg = cgb + L
// (cgb = role*4, wave-uniform). cst indexed by literal L -> stays in regs.

// acc init reads (bias,wih) directly from LDS (read-only -> barrier-safe).
#define INITACC(L, acc) do {                                                  \
  const int cg_ = cgb + (L);                                                  \
  _Pragma("unroll") for (int g_ = 0; g_ < 4; ++g_) {                          \
    const int b_ = g_ * 128 + cg_ * 16 + quad * 4;                            \
    const float4 p0_ = *(const float4*)&bw[b_];                               \
    const float4 p1_ = *(const float4*)&bw[b_ + 2];                           \
    acc[g_][0] = p0_.x + xv * p0_.y;                                          \
    acc[g_][1] = p0_.z + xv * p0_.w;                                          \
    acc[g_][2] = p1_.x + xv * p1_.y;                                          \
    acc[g_][3] = p1_.z + xv * p1_.w;                                          \
  }                                                                           \
} while (0)

// load the 4 A-fragments (one per gate) of k-tile KT for local cg L
#define LDA(buf, L, KT) do {                                                  \
  _Pragma("unroll") for (int g_ = 0; g_ < 4; ++g_)                            \
    buf[g_] = *(const half8*)&Wl[                                             \
        (size_t)(((g_ * 8 + cgb + (L)) * 4 + (KT)) * 64 + ln) * 8];           \
} while (0)

// 4 MFMAs (one per gate) for k-tile KT
#define MFA(acc, buf, KT) do {                                                \
  _Pragma("unroll") for (int g_ = 0; g_ < 4; ++g_)                            \
    acc[g_] = __builtin_amdgcn_mfma_f32_16x16x32_f16(                         \
        buf[g_], Bf[(KT)], acc[g_], 0, 0, 0);                                 \
} while (0)

#define PHASE4(L, acc) do {                                                   \
  const int cg_ = cgb + (L);                                                  \
  half4v hpack;                                                               \
  _Pragma("unroll") for (int r_ = 0; r_ < 4; ++r_) {                          \
    const float Be = __builtin_amdgcn_exp2f(-acc[0][r_]);                     \
    const float Ae = __builtin_amdgcn_exp2f(-acc[1][r_]);                     \
    const float De = __builtin_amdgcn_exp2f(acc[2][r_]);                      \
    const float Ee = __builtin_amdgcn_exp2f(-acc[3][r_]);                     \
    const float Ap = Ae + 1.f;                                                \
    const float Bp = Be + 1.f;                                                \
    const float Dp = De + 1.f;                                                \
    const float Nn = cst[(L) * 4 + r_] * Bp * Dp + Ap * (De - 1.f);           \
    const float cv = Nn * __builtin_amdgcn_rcpf(Ap * Bp * Dp);                \
    cst[(L) * 4 + r_] = cv;                                                   \
    const float cvc = fminf(fmaxf(cv, -10.f), 10.f);                          \
    const float Fe = __builtin_amdgcn_exp2f(K2E * cvc);                       \
    hpack[r_] = (_Float16)((Fe - 1.f) *                                       \
                __builtin_amdgcn_rcpf((Ee + 1.f) * (Fe + 1.f)));              \
  }                                                                           \
  const int lp_ = nl + 16 * (2 * (cg_ & 1) + wq_hi);                          \
  *(half4v*)&myscr[(cg_ >> 1) * 512 + lp_ * 8 + j0] = hpack;                  \
} while (0)

#define SB __builtin_amdgcn_sched_barrier(0)

// One LSTM step for one role (4 cg groups). Per body: issue 8 frag loads,
// SB-pin them before prev cg's PHASE4 (VALU covers latency), then MFA with
// staggered kt2/kt3 loads. Depth-2 acc: PHASE4(L) runs in body L+1.
#define LSTM_STEP() do {                                                      \
  half8 Bf[4];                                                                \
  _Pragma("unroll") for (int kt_ = 0; kt_ < 4; ++kt_)                         \
    Bf[kt_] = *(const half8*)&myscr[kt_ * 512 + ln * 8];                      \
  floatx4 accA[4], accB[4];                                                   \
  half8 Aa[4], Ab[4];                                                         \
  /* body 0 (no pending phase4) */                                            \
  INITACC(0, accA);                                                           \
  LDA(Aa, 0, 0); LDA(Ab, 0, 1);                                               \
  __syncthreads();  /* bar1: all h reads done; writes may start */            \
  MFA(accA, Aa, 0); LDA(Aa, 0, 2);                                            \
  MFA(accA, Ab, 1); LDA(Ab, 0, 3);                                            \
  MFA(accA, Aa, 2); MFA(accA, Ab, 3);                                         \
  /* body 1 */                                                                \
  INITACC(1, accB); LDA(Aa, 1, 0); LDA(Ab, 1, 1);                             \
  SB; PHASE4(0, accA);                                                        \
  MFA(accB, Aa, 0); LDA(Aa, 1, 2);                                            \
  MFA(accB, Ab, 1); LDA(Ab, 1, 3);                                            \
  MFA(accB, Aa, 2); MFA(accB, Ab, 3);                                         \
  /* body 2 */                                                                \
  INITACC(2, accA); LDA(Aa, 2, 0); LDA(Ab, 2, 1);                             \
  SB; PHASE4(1, accB);                                                        \
  MFA(accA, Aa, 0); LDA(Aa, 2, 2);                                            \
  MFA(accA, Ab, 1); LDA(Ab, 2, 3);                                            \
  MFA(accA, Aa, 2); MFA(accA, Ab, 3);                                         \
  /* body 3 */                                                                \
  INITACC(3, accB); LDA(Aa, 3, 0); LDA(Ab, 3, 1);                             \
  SB; PHASE4(2, accA);                                                        \
  MFA(accB, Aa, 0); LDA(Aa, 3, 2);                                            \
  MFA(accB, Ab, 1); LDA(Ab, 3, 3);                                            \
  MFA(accB, Aa, 2); MFA(accB, Ab, 3);                                         \
  PHASE4(3, accB);                                                            \
  __syncthreads();  /* bar2: all writes done before next step's reads */      \
} while (0)

// ---------------------------------------------------------------------------
// Wave-pair LSTM. Block = 640 threads (10 waves), 5 groups x 16 nodes.
// Group g's pair: wave 2g (role 0, cg0-3) + wave 2g+1 (role 1, cg4-7).
__global__ __attribute__((amdgpu_flat_work_group_size(BTHR, BTHR),
                          amdgpu_waves_per_eu(3, 3)))
void lstm_stream_kernel(
    const float* __restrict__ xfeat, const _Float16* __restrict__ Wpack,
    const float* __restrict__ Wih, const float* __restrict__ bih,
    const float* __restrict__ bhh, float* __restrict__ x1)
{
  extern __shared__ char dynlds[];
  _Float16* Wl  = (_Float16*)dynlds;                    // [128 tiles][64 lanes][8]
  float2*   bw  = (float2*)(dynlds + LDS_W);            // [512] (bias, wih) pre-scaled
  _Float16* scr = (_Float16*)(dynlds + LDS_W + LDS_BW); // [5][2048]

  const int tid  = threadIdx.x;   // 0..639
  const int wv   = tid >> 6;      // wave 0..9
  const int grp  = wv >> 1;       // node group 0..4
  const int role = wv & 1;        // 0: cg0-3, 1: cg4-7
  const int cgb  = role * 4;
  const int ln   = tid & 63;
  const int nl   = ln & 15;       // node within group
  const int quad = ln >> 4;
  const int n0   = blockIdx.x * NBB + grp * NBW;

  // stage packed Whh -> LDS (coalesced float4)
  {
    const float4* src = (const float4*)Wpack;
    float4* dst = (float4*)Wl;
    for (int i = tid; i < LDS_W / 16; i += BTHR) dst[i] = src[i];
  }
  for (int i = tid; i < 512; i += BTHR) {
    const float sc = ((i >> 7) == 2) ? K2E : L2E;
    bw[i] = make_float2((bih[i] + bhh[i]) * sc, Wih[i] * sc);
  }
  {
    float4* z = (float4*)scr;
    for (int i = tid; i < LDS_SCR / 16; i += BTHR)
      z[i] = make_float4(0.f, 0.f, 0.f, 0.f);
  }
  __syncthreads();

  _Float16* myscr = scr + grp * 2048;
  const float* xrow = xfeat + (size_t)(n0 + nl) * T_STEPS;

  float cst[16];
  #pragma unroll
  for (int i = 0; i < 16; ++i) cst[i] = 0.f;

  const int wq_hi = quad >> 1;
  const int j0    = (quad & 1) * 4;

  float xv = xrow[0];

  #pragma unroll 1
  for (int t = 0; t < T_STEPS; ++t) {
    const float xn = xrow[(t + 1 <= 63) ? (t + 1) : 63];
    LSTM_STEP();
    xv = xn;
  }

  // epilogue: final h sits in scratch in B-frag order -> x1 = relu(h).
  // role 0 writes kt banks 0-1, role 1 banks 2-3.
  #pragma unroll
  for (int k = 0; k < 2; ++k) {
    const int kt = role * 2 + k;
    const half8 hf = *(const half8*)&myscr[kt * 512 + ln * 8];
    float* dst = x1 + (size_t)(n0 + nl) * HDIM + kt * 32 + quad * 8;
    float4 o0, o1;
    o0.x = fmaxf((float)hf[0], 0.f); o0.y = fmaxf((float)hf[1], 0.f);
    o0.z = fmaxf((float)hf[2], 0.f); o0.w = fmaxf((float)hf[3], 0.f);
    o1.x = fmaxf((float)hf[4], 0.f); o1.y = fmaxf((float)hf[5], 0.f);
    o1.z = fmaxf((float)hf[6], 0.f); o1.w = fmaxf((float)hf[7], 0.f);
    *(float4*)dst = o0;
    *(float4*)(dst + 4) = o1;
  }
}

// ---------------------------------------------------------------------------
// Y[n][j] = sum_k X[n][k] * W[j][k].  32 nodes/block, W LDS-tiled in 64-row chunks.
template <int J>
__global__ __launch_bounds__(256) void gemm_xw(
    const float* __restrict__ X, const float* __restrict__ W, float* __restrict__ Y)
{
  __shared__ float Xs[32 * 132];
  __shared__ float Ws[64 * 132];
  const int tid = threadIdx.x;
  const int n0  = blockIdx.x * 32;
  for (int i = tid; i < 32 * 128; i += 256) {
    int nn = i >> 7, k = i & 127;
    Xs[nn * 132 + k] = X[(n0 + nn) * 128 + k];
  }
  const int nl = tid >> 3;
  const int jb = tid & 7;
  for (int c0 = 0; c0 < J; c0 += 64) {
    __syncthreads();
    for (int i = tid; i < 64 * 128; i += 256) {
      int r = i >> 7, k = i & 127;
      Ws[r * 132 + k] = W[(c0 + r) * 128 + k];
    }
    __syncthreads();
    float acc[8];
    #pragma unroll
    for (int m = 0; m < 8; ++m) acc[m] = 0.f;
    for (int k0 = 0; k0 < 128; k0 += 8) {
      float xr[8];
      #pragma unroll
      for (int r = 0; r < 8; ++r) xr[r] = Xs[nl * 132 + k0 + r];
      #pragma unroll
      for (int m = 0; m < 8; ++m) {
        const float* w = &Ws[(jb + (m << 3)) * 132 + k0];
        float a = acc[m];
        #pragma unroll
        for (int r = 0; r < 8; ++r) a += xr[r] * w[r];
        acc[m] = a;
      }
    }
    #pragma unroll
    for (int m = 0; m < 8; ++m)
      Y[(n0 + nl) * J + c0 + jb + (m << 3)] = acc[m];
  }
}

// ---------------------------------------------------------------------------
__global__ void zero_kernel(float* __restrict__ deg, int* __restrict__ cnt,
                            float* __restrict__ accum)
{
  int i = blockIdx.x * 256 + threadIdx.x;
  if (i < N_NODES) { deg[i] = 0.f; cnt[i] = 0; }
  if (i < JOUT) accum[i] = 0.f;
}

__global__ void count_kernel(const int* __restrict__ ei, const float* __restrict__ ew,
                             int* __restrict__ cnt, float* __restrict__ deg)
{
  int e = blockIdx.x * 256 + threadIdx.x;
  int c = ei[N_EDGES + e];
  atomicAdd(&cnt[c], 1);
  atomicAdd(&deg[c], ew[e]);
}

// shuffle-based exclusive scan: thread t owns elements [t*20, t*20+20).
__global__ __launch_bounds__(1024) void scan_kernel(
    const int* __restrict__ cnt, int* __restrict__ rowptr, int* __restrict__ cursor,
    const float* __restrict__ deg, float* __restrict__ dinv)
{
  const int tid  = threadIdx.x;
  const int lane = tid & 63;
  const int wv   = tid >> 6;        // 16 waves
  const int base = tid * 20;
  int vals[20];
  int sum = 0;
  if (tid < 1000) {
    #pragma unroll
    for (int j = 0; j < 20; ++j) { vals[j] = sum; sum += cnt[base + j]; }
  }
  int inc = sum;
  #pragma unroll
  for (int off = 1; off < 64; off <<= 1) {
    int t = __shfl_up(inc, off);
    if (lane >= off) inc += t;
  }
  __shared__ int wtot[16];
  __shared__ int wpre[16];
  if (lane == 63) wtot[wv] = inc;
  __syncthreads();
  if (tid == 0) {
    int s = 0;
    for (int i = 0; i < 16; ++i) { wpre[i] = s; s += wtot[i]; }
    rowptr[N_NODES] = s;
  }
  __syncthreads();
  if (tid < 1000) {
    int off = wpre[wv] + (inc - sum);
    #pragma unroll
    for (int j = 0; j < 20; ++j) {
      int v = off + vals[j];
      rowptr[base + j] = v;
      cursor[base + j] = v;
    }
  }
  for (int i = tid; i < N_NODES; i += 1024)
    dinv[i] = rsqrtf(deg[i] + 1.0f);   // +1 = self-loop weight
}

__global__ void fill_kernel(const int* __restrict__ ei, const float* __restrict__ ew,
                            const float* __restrict__ dinv, int* __restrict__ cursor,
                            int* __restrict__ esrc, float* __restrict__ ewn)
{
  int e = blockIdx.x * 256 + threadIdx.x;
  int r = ei[e];
  int c = ei[N_EDGES + e];
  int p = atomicAdd(&cursor[c], 1);
  esrc[p] = r;
  ewn[p]  = ew[e] * dinv[r];   // pre-scale by dinv[row]
}

// ---------------------------------------------------------------------------
// GCN aggregation: one wave per destination node; 64-edge tiles staged in LDS,
// broadcast loop unrolled x4. x2 = relu(agg + b).
__global__ __launch_bounds__(256) void gcn_agg_kernel(
    const float* __restrict__ y, const float* __restrict__ dinv,
    const int* __restrict__ rowptr, const int* __restrict__ esrc,
    const float* __restrict__ ewn, const float* __restrict__ gcn_b,
    float* __restrict__ x2)
{
  __shared__ float2 stg[4][64];
  const int lane = threadIdx.x & 63;
  const int wv = threadIdx.x >> 6;
  const int c = blockIdx.x * 4 + wv;
  const float dc = dinv[c];
  const float2* y2 = (const float2*)y;
  float2 yc = y2[c * 64 + lane];
  float ax = yc.x * dc * dc, ay = yc.y * dc * dc;   // self-loop term
  const int e0 = rowptr[c], e1 = rowptr[c + 1];
  for (int tb = e0; tb < e1; tb += 64) {
    const int cnt = min(64, e1 - tb);
    const int k = tb + lane;
    if (k < e1) stg[wv][lane] = make_float2(__int_as_float(esrc[k]), ewn[k] * dc);
    __builtin_amdgcn_wave_barrier();
    int i = 0;
    for (; i + 4 <= cnt; i += 4) {
      float2 p0 = stg[wv][i],     p1 = stg[wv][i + 1];
      float2 p2 = stg[wv][i + 2], p3 = stg[wv][i + 3];
      const float2 a0 = y2[(size_t)__float_as_int(p0.x) * 64 + lane];
      const float2 a1 = y2[(size_t)__float_as_int(p1.x) * 64 + lane];
      const float2 a2 = y2[(size_t)__float_as_int(p2.x) * 64 + lane];
      const float2 a3 = y2[(size_t)__float_as_int(p3.x) * 64 + lane];
      ax += a0.x * p0.y + a1.x * p1.y + a2.x * p2.y + a3.x * p3.y;
      ay += a0.y * p0.y + a1.y * p1.y + a2.y * p2.y + a3.y * p3.y;
    }
    for (; i < cnt; ++i) {
      float2 p0 = stg[wv][i];
      const float2 a0 = y2[(size_t)__float_as_int(p0.x) * 64 + lane];
      ax += a0.x * p0.y; ay += a0.y * p0.y;
    }
    __builtin_amdgcn_wave_barrier();
  }
  int j0 = lane * 2;
  x2[c * 128 + j0]     = fmaxf(ax + gcn_b[j0], 0.f);
  x2[c * 128 + j0 + 1] = fmaxf(ay + gcn_b[j0 + 1], 0.f);
}

// ---------------------------------------------------------------------------
// Per-node attention logits: a_src/a_dst [N][4] (padded float4)
__global__ __launch_bounds__(256) void gat_att_kernel(
    const float* __restrict__ xh, const float* __restrict__ att_src,
    const float* __restrict__ att_dst, float4* __restrict__ asrc,
    float4* __restrict__ adst)
{
  const int lane = threadIdx.x & 63;
  const int nd = blockIdx.x * 4 + (threadIdx.x >> 6);
  float s[3], d[3];
  #pragma unroll
  for (int h = 0; h < 3; ++h) {
    float xv = xh[nd * JOUT + h * 64 + lane];
    s[h] = xv * att_src[h * 64 + lane];
    d[h] = xv * att_dst[h * 64 + lane];
  }
  #pragma unroll
  for (int off = 1; off < 64; off <<= 1) {
    #pragma unroll
    for (int h = 0; h < 3; ++h) {
      s[h] += __shfl_xor(s[h], off);
      d[h] += __shfl_xor(d[h], off);
    }
  }
  if (lane == 0) {
    asrc[nd] = make_float4(s[0], s[1], s[2], 0.f);
    adst[nd] = make_float4(d[0], d[1], d[2], 0.f);
  }
}

// GAT: softmax over incoming edges (incl self-loop) + weighted agg.
// One wave per node; first-tile alpha cached in regs; 64-edge LDS-staged tiles.
__global__ __launch_bounds__(256) void gat_agg_kernel(
    const float* __restrict__ xh, const float4* __restrict__ asrc,
    const float4* __restrict__ adst, const int* __restrict__ rowptr,
    const int* __restrict__ esrc, float* __restrict__ accum)
{
  __shared__ float4 cstg[4][64];
  const int lane = threadIdx.x & 63;
  const int wv = threadIdx.x >> 6;
  const int c = blockIdx.x * 4 + wv;
  const int e0 = rowptr[c], e1 = rowptr[c + 1];
  float4 adc = adst[c];
  float4 asc = asrc[c];
  float self0 = lrelu(asc.x + adc.x);
  float self1 = lrelu(asc.y + adc.y);
  float self2 = lrelu(asc.z + adc.z);

  const bool has = (e0 + lane < e1);
  int s_first = 0;
  float v0 = -3.0e38f, v1 = -3.0e38f, v2 = -3.0e38f;
  if (has) {
    s_first = esrc[e0 + lane];
    float4 av = asrc[s_first];
    v0 = lrelu(av.x + adc.x);
    v1 = lrelu(av.y + adc.y);
    v2 = lrelu(av.z + adc.z);
  }
  float m0 = fmaxf(self0, v0), m1 = fmaxf(self1, v1), m2 = fmaxf(self2, v2);
  for (int k = e0 + 64 + lane; k < e1; k += 64) {
    float4 av = asrc[esrc[k]];
    m0 = fmaxf(m0, lrelu(av.x + adc.x));
    m1 = fmaxf(m1, lrelu(av.y + adc.y));
    m2 = fmaxf(m2, lrelu(av.z + adc.z));
  }
  #pragma unroll
  for (int off = 1; off < 64; off <<= 1) {
    m0 = fmaxf(m0, __shfl_xor(m0, off));
    m1 = fmaxf(m1, __shfl_xor(m1, off));
    m2 = fmaxf(m2, __shfl_xor(m2, off));
  }
  float ex0 = has ? __expf(v0 - m0) : 0.f;
  float ex1 = has ? __expf(v1 - m1) : 0.f;
  float ex2 = has ? __expf(v2 - m2) : 0.f;
  float d0 = ex0, d1 = ex1, d2 = ex2;
  for (int k = e0 + 64 + lane; k < e1; k += 64) {
    float4 av = asrc[esrc[k]];
    d0 += __expf(lrelu(av.x + adc.x) - m0);
    d1 += __expf(lrelu(av.y + adc.y) - m1);
    d2 += __expf(lrelu(av.z + adc.z) - m2);
  }
  #pragma unroll
  for (int off = 1; off < 64; off <<= 1) {
    d0 += __shfl_xor(d0, off);
    d1 += __shfl_xor(d1, off);
    d2 += __shfl_xor(d2, off);
  }
  float se0 = __expf(self0 - m0), se1 = __expf(self1 - m1), se2 = __expf(self2 - m2);
  d0 += se0; d1 += se1; d2 += se2;
  float iv0 = 1.f / d0, iv1 = 1.f / d1, iv2 = 1.f / d2;

  float o0 = se0 * iv0 * xh[c * JOUT + lane];
  float o1 = se1 * iv1 * xh[c * JOUT + 64 + lane];
  float o2 = se2 * iv2 * xh[c * JOUT + 128 + lane];

  for (int tb = e0; tb < e1; tb += 64) {
    const int cnt = min(64, e1 - tb);
    if (tb == e0) {
      if (has)
        cstg[wv][lane] = make_float4(__int_as_float(s_first),
                                     ex0 * iv0, ex1 * iv1, ex2 * iv2);
    } else {
      const int k = tb + lane;
      if (k < e1) {
        int s = esrc[k];
        float4 av = asrc[s];
        cstg[wv][lane] = make_float4(__int_as_float(s),
            __expf(lrelu(av.x + adc.x) - m0) * iv0,
            __expf(lrelu(av.y + adc.y) - m1) * iv1,
            __expf(lrelu(av.z + adc.z) - m2) * iv2);
      }
    }
    __builtin_amdgcn_wave_barrier();
    int i = 0;
    for (; i + 2 <= cnt; i += 2) {
      float4 q0 = cstg[wv][i], q1 = cstg[wv][i + 1];
      const float* r0 = xh + (size_t)__float_as_int(q0.x) * JOUT;
      const float* r1 = xh + (size_t)__float_as_int(q1.x) * JOUT;
      float a0 = r0[lane], b0 = r0[64 + lane], g0 = r0[128 + lane];
      float a1 = r1[lane], b1 = r1[64 + lane], g1 = r1[128 + lane];
      o0 += q0.y * a0 + q1.y * a1;
      o1 += q0.z * b0 + q1.z * b1;
      o2 += q0.w * g0 + q1.w * g1;
    }
    for (; i < cnt; ++i) {
      float4 q0 = cstg[wv][i];
      const float* r0 = xh + (size_t)__float_as_int(q0.x) * JOUT;
      o0 += q0.y * r0[lane];
      o1 += q0.z * r0[64 + lane];
      o2 += q0.w * r0[128 + lane];
    }
    __builtin_amdgcn_wave_barrier();
  }

  __shared__ float red[4][JOUT];
  red[wv][lane]       = o0;
  red[wv][64 + lane]  = o1;
  red[wv][128 + lane] = o2;
  __syncthreads();
  if (threadIdx.x < JOUT) {
    float sum = red[0][threadIdx.x] + red[1][threadIdx.x] +
                red[2][threadIdx.x] + red[3][threadIdx.x];
    atomicAdd(&accum[threadIdx.x], sum);
  }
}

__global__ void finalize_kernel(const float* __restrict__ accum,
                                const float* __restrict__ gat_b,
                                float* __restrict__ out)
{
  int j = threadIdx.x;
  if (j < JOUT) out[j] = accum[j] * (1.0f / N_NODES) + gat_b[j];
}

// ---------------------------------------------------------------------------
extern "C" void kernel_launch(void* const* d_in, const int* in_sizes, int n_in,
                              void* d_out, int out_size, void* d_ws, size_t ws_size,
                              hipStream_t stream)
{
  const float* xfeat = (const float*)d_in[0];
  const int*   eidx  = (const int*)d_in[1];
  const float* eattr = (const float*)d_in[2];
  const float* Wih   = (const float*)d_in[3];
  const float* Whh   = (const float*)d_in[4];
  const float* bihp  = (const float*)d_in[5];
  const float* bhhp  = (const float*)d_in[6];
  const float* gcnW  = (const float*)d_in[7];
  const float* gcnb  = (const float*)d_in[8];
  const float* gatW  = (const float*)d_in[9];
  const float* attS  = (const float*)d_in[10];
  const float* attD  = (const float*)d_in[11];
  const float* gatb  = (const float*)d_in[12];
  float* out = (float*)d_out;

  char* ws = (char*)d_ws;
  size_t off = 0;
  auto alloc = [&](size_t bytes) {
    char* p = ws + off;
    off += (bytes + 255) & ~size_t(255);
    return p;
  };
  float*     x1     = (float*)alloc((size_t)N_NODES * 128 * 4);
  float*     y      = (float*)alloc((size_t)N_NODES * 128 * 4);
  float*     x2     = (float*)alloc((size_t)N_NODES * 128 * 4);
  float*     xh     = (float*)alloc((size_t)N_NODES * 192 * 4);
  float4*    asrc   = (float4*)alloc((size_t)N_NODES * 16);
  float4*    adst   = (float4*)alloc((size_t)N_NODES * 16);
  float*     deg    = (float*)alloc((size_t)N_NODES * 4);
  float*     dinv   = (float*)alloc((size_t)N_NODES * 4);
  int*       cnt    = (int*)alloc((size_t)N_NODES * 4);
  int*       rowptr = (int*)alloc((size_t)(N_NODES + 1) * 4);
  int*       cursor = (int*)alloc((size_t)N_NODES * 4);
  int*       esrc   = (int*)alloc((size_t)N_EDGES * 4);
  float*     ewn    = (float*)alloc((size_t)N_EDGES * 4);
  float*     accum  = (float*)alloc(JOUT * 4);
  _Float16*  wpack  = (_Float16*)alloc(131072);

  // opt-in to >64KB dynamic LDS for the wave-pair LSTM (idempotent)
  hipFuncSetAttribute((const void*)lstm_stream_kernel,
                      hipFuncAttributeMaxDynamicSharedMemorySize, LDS_TOTAL);

  zero_kernel<<<(N_NODES + 255) / 256, 256, 0, stream>>>(deg, cnt, accum);
  pack_whh_kernel<<<32, 256, 0, stream>>>(Whh, wpack);
  lstm_stream_kernel<<<N_NODES / NBB, BTHR, LDS_TOTAL, stream>>>(
      xfeat, wpack, Wih, bihp, bhhp, x1);
  count_kernel<<<N_EDGES / 256, 256, 0, stream>>>(eidx, eattr, cnt, deg);
  scan_kernel<<<1, 1024, 0, stream>>>(cnt, rowptr, cursor, deg, dinv);
  fill_kernel<<<N_EDGES / 256, 256, 0, stream>>>(eidx, eattr, dinv, cursor, esrc, ewn);
  gemm_xw<128><<<N_NODES / 32, 256, 0, stream>>>(x1, gcnW, y);
  gcn_agg_kernel<<<N_NODES / 4, 256, 0, stream>>>(y, dinv, rowptr, esrc, ewn, gcnb, x2);
  gemm_xw<192><<<N_NODES / 32, 256, 0, stream>>>(x2, gatW, xh);
  gat_att_kernel<<<N_NODES / 4, 256, 0, stream>>>(xh, attS, attD, asrc, adst);
  gat_agg_kernel<<<N_NODES / 4, 256, 0, stream>>>(xh, asrc, adst, rowptr, esrc, accum);
  finalize_kernel<<<1, 256, 0, stream>>>(accum, gatb, out);
}

// Round 7
// 769.571 us; speedup vs baseline: 1.1455x; 1.0373x over previous
//
#include <hip/hip_runtime.h>

// TemporalGAT: LSTM(T=64,H=128) -> ReLU -> GCNConv -> ReLU -> GATConv(3x64) -> mean
// Round 21: two levers.
// (1) Graph path (414us of 798): gcn_agg/gat_agg gather 328MB/492MB of y/xh
//     rows per iteration (640K edges x 512B/768B). Store x1, y, xh in fp16:
//     x1 is free (h already fp16-quantized); y/xh add ~5e-4 random rounding
//     that the final 20000-node mean averages down. Gather bytes halved.
// (2) LSTM (384us, VALUBusy 48.8 with ~3.5x the hand-counted VALU work):
//     hoist per-lane LDS base pointers (Wl+ln*8+cgb*2048, bw+quad*4+cgb*16,
//     myscr+ln*8) out of the t-loop so all ~100 ds_reads/step become
//     base + compile-time immediate instead of full per-access address math.

#define N_NODES 20000
#define T_STEPS 64
#define N_EDGES 640000
#define HDIM    128
#define JOUT    192   // HEADS*OUT = 3*64
#define NEG_SLOPE 0.2f
#define NBW     16    // nodes per group
#define NGRP    5
#define NBB     (NBW * NGRP)   // 80 nodes per block
#define BTHR    640            // 10 waves: 5 groups x 2 roles
#define LDS_W     131072                  // packed Whh fp16
#define LDS_BW    4096                    // (bias, wih) float2[512]
#define LDS_SCR   (NGRP * 4096)           // per-group h scratch
#define LDS_TOTAL (LDS_W + LDS_BW + LDS_SCR)   // 155648

#define L2E  1.4426950408889634f
#define K2E  2.8853900817779268f   // 2*log2(e)

typedef _Float16 half8 __attribute__((ext_vector_type(8)));
typedef _Float16 half4v __attribute__((ext_vector_type(4)));
typedef _Float16 half2v __attribute__((ext_vector_type(2)));
typedef float floatx4 __attribute__((ext_vector_type(4)));

__device__ __forceinline__ float lrelu(float x) { return x > 0.f ? x : NEG_SLOPE * x; }

// ---------------------------------------------------------------------------
// Pre-pack Whh (fp32 [512][128]) into fp16 MFMA A-fragment order, PRE-SCALED
// into the exp2 domain: rows of gates i,f,o scaled by log2e, g-gate rows by
// 2*log2e (so exp(2*g) becomes exp2(g')).
__global__ void pack_whh_kernel(const float* __restrict__ Whh,
                                _Float16* __restrict__ Wpack)
{
  int i = blockIdx.x * 256 + threadIdx.x;   // 0..8191
  int tile = i >> 6, lane = i & 63;
  int nt = tile >> 2, kt = tile & 3;
  int row = nt * 16 + (lane & 15);
  int c0  = kt * 32 + (lane >> 4) * 8;
  const float sc = ((row >> 7) == 2) ? K2E : L2E;
  half8 v;
  #pragma unroll
  for (int j = 0; j < 8; ++j)
    v[j] = (_Float16)(Whh[row * 128 + c0 + j] * sc);
  *(half8*)&Wpack[(size_t)i * 8] = v;
}

// ---------------------------------------------------------------------------
// Building blocks. L is a LITERAL local cg index (0..3); all LDS accesses are
// hoisted-lane-base + compile-time offsets.

#define INITACC(L, acc) do {                                                  \
  _Pragma("unroll") for (int g_ = 0; g_ < 4; ++g_) {                          \
    const float4 p0_ = *(const float4*)&bwRole[g_ * 128 + (L) * 16];          \
    const float4 p1_ = *(const float4*)&bwRole[g_ * 128 + (L) * 16 + 2];      \
    acc[g_][0] = p0_.x + xv * p0_.y;                                          \
    acc[g_][1] = p0_.z + xv * p0_.w;                                          \
    acc[g_][2] = p1_.x + xv * p1_.y;                                          \
    acc[g_][3] = p1_.z + xv * p1_.w;                                          \
  }                                                                           \
} while (0)

// load the 4 A-fragments (one per gate) of k-tile KT for local cg L
#define LDA(buf, L, KT) do {                                                  \
  _Pragma("unroll") for (int g_ = 0; g_ < 4; ++g_)                            \
    buf[g_] = *(const half8*)&WlRole[g_ * 16384 + (L) * 2048 + (KT) * 512];   \
} while (0)

// 4 MFMAs (one per gate) for k-tile KT
#define MFA(acc, buf, KT) do {                                                \
  _Pragma("unroll") for (int g_ = 0; g_ < 4; ++g_)                            \
    acc[g_] = __builtin_amdgcn_mfma_f32_16x16x32_f16(                         \
        buf[g_], Bf[(KT)], acc[g_], 0, 0, 0);                                 \
} while (0)

#define PHASE4(L, acc) do {                                                   \
  const int cg_ = cgb + (L);                                                  \
  half4v hpack;                                                               \
  _Pragma("unroll") for (int r_ = 0; r_ < 4; ++r_) {                          \
    const float Be = __builtin_amdgcn_exp2f(-acc[0][r_]);                     \
    const float Ae = __builtin_amdgcn_exp2f(-acc[1][r_]);                     \
    const float De = __builtin_amdgcn_exp2f(acc[2][r_]);                      \
    const float Ee = __builtin_amdgcn_exp2f(-acc[3][r_]);                     \
    const float Ap = Ae + 1.f;                                                \
    const float Bp = Be + 1.f;                                                \
    const float Dp = De + 1.f;                                                \
    const float Nn = cst[(L) * 4 + r_] * Bp * Dp + Ap * (De - 1.f);           \
    const float cv = Nn * __builtin_amdgcn_rcpf(Ap * Bp * Dp);                \
    cst[(L) * 4 + r_] = cv;                                                   \
    const float cvc = fminf(fmaxf(cv, -10.f), 10.f);                          \
    const float Fe = __builtin_amdgcn_exp2f(K2E * cvc);                       \
    hpack[r_] = (_Float16)((Fe - 1.f) *                                       \
                __builtin_amdgcn_rcpf((Ee + 1.f) * (Fe + 1.f)));              \
  }                                                                           \
  const int lp_ = nl + 16 * (2 * (cg_ & 1) + wq_hi);                          \
  *(half4v*)&myscr[(cg_ >> 1) * 512 + lp_ * 8 + j0] = hpack;                  \
} while (0)

#define SB __builtin_amdgcn_sched_barrier(0)

// One LSTM step for one role (4 cg groups). Per body: issue 8 frag loads,
// SB-pin them before prev cg's PHASE4 (VALU covers latency), then MFA with
// staggered kt2/kt3 loads. Depth-2 acc: PHASE4(L) runs in body L+1.
#define LSTM_STEP() do {                                                      \
  half8 Bf[4];                                                                \
  _Pragma("unroll") for (int kt_ = 0; kt_ < 4; ++kt_)                         \
    Bf[kt_] = *(const half8*)&scrLane[kt_ * 512];                             \
  floatx4 accA[4], accB[4];                                                   \
  half8 Aa[4], Ab[4];                                                         \
  /* body 0 (no pending phase4) */                                            \
  INITACC(0, accA);                                                           \
  LDA(Aa, 0, 0); LDA(Ab, 0, 1);                                               \
  __syncthreads();  /* bar1: all h reads done; writes may start */            \
  MFA(accA, Aa, 0); LDA(Aa, 0, 2);                                            \
  MFA(accA, Ab, 1); LDA(Ab, 0, 3);                                            \
  MFA(accA, Aa, 2); MFA(accA, Ab, 3);                                         \
  /* body 1 */                                                                \
  INITACC(1, accB); LDA(Aa, 1, 0); LDA(Ab, 1, 1);                             \
  SB; PHASE4(0, accA);                                                        \
  MFA(accB, Aa, 0); LDA(Aa, 1, 2);                                            \
  MFA(accB, Ab, 1); LDA(Ab, 1, 3);                                            \
  MFA(accB, Aa, 2); MFA(accB, Ab, 3);                                         \
  /* body 2 */                                                                \
  INITACC(2, accA); LDA(Aa, 2, 0); LDA(Ab, 2, 1);                             \
  SB; PHASE4(1, accB);                                                        \
  MFA(accA, Aa, 0); LDA(Aa, 2, 2);                                            \
  MFA(accA, Ab, 1); LDA(Ab, 2, 3);                                            \
  MFA(accA, Aa, 2); MFA(accA, Ab, 3);                                         \
  /* body 3 */                                                                \
  INITACC(3, accB); LDA(Aa, 3, 0); LDA(Ab, 3, 1);                             \
  SB; PHASE4(2, accA);                                                        \
  MFA(accB, Aa, 0); LDA(Aa, 3, 2);                                            \
  MFA(accB, Ab, 1); LDA(Ab, 3, 3);                                            \
  MFA(accB, Aa, 2); MFA(accB, Ab, 3);                                         \
  PHASE4(3, accB);                                                            \
  __syncthreads();  /* bar2: all writes done before next step's reads */      \
} while (0)

// ---------------------------------------------------------------------------
// Wave-pair LSTM. Block = 640 threads (10 waves), 5 groups x 16 nodes.
// Group g's pair: wave 2g (role 0, cg0-3) + wave 2g+1 (role 1, cg4-7).
__global__ __attribute__((amdgpu_flat_work_group_size(BTHR, BTHR),
                          amdgpu_waves_per_eu(3, 3)))
void lstm_stream_kernel(
    const float* __restrict__ xfeat, const _Float16* __restrict__ Wpack,
    const float* __restrict__ Wih, const float* __restrict__ bih,
    const float* __restrict__ bhh, _Float16* __restrict__ x1)
{
  extern __shared__ char dynlds[];
  _Float16* Wl  = (_Float16*)dynlds;                    // [128 tiles][64 lanes][8]
  float2*   bw  = (float2*)(dynlds + LDS_W);            // [512] (bias, wih) pre-scaled
  _Float16* scr = (_Float16*)(dynlds + LDS_W + LDS_BW); // [5][2048]

  const int tid  = threadIdx.x;   // 0..639
  const int wv   = tid >> 6;      // wave 0..9
  const int grp  = wv >> 1;       // node group 0..4
  const int role = wv & 1;        // 0: cg0-3, 1: cg4-7
  const int cgb  = role * 4;
  const int ln   = tid & 63;
  const int nl   = ln & 15;       // node within group
  const int quad = ln >> 4;
  const int n0   = blockIdx.x * NBB + grp * NBW;

  // stage packed Whh -> LDS (coalesced float4)
  {
    const float4* src = (const float4*)Wpack;
    float4* dst = (float4*)Wl;
    for (int i = tid; i < LDS_W / 16; i += BTHR) dst[i] = src[i];
  }
  for (int i = tid; i < 512; i += BTHR) {
    const float sc = ((i >> 7) == 2) ? K2E : L2E;
    bw[i] = make_float2((bih[i] + bhh[i]) * sc, Wih[i] * sc);
  }
  {
    float4* z = (float4*)scr;
    for (int i = tid; i < LDS_SCR / 16; i += BTHR)
      z[i] = make_float4(0.f, 0.f, 0.f, 0.f);
  }
  __syncthreads();

  _Float16* myscr = scr + grp * 2048;
  // hoisted per-lane bases: all hot-loop LDS accesses = base + literal offset
  const _Float16* WlRole  = Wl + (size_t)cgb * 2048 + (size_t)ln * 8;
  const float2*   bwRole  = bw + cgb * 16 + quad * 4;
  const _Float16* scrLane = myscr + (size_t)ln * 8;
  const float* xrow = xfeat + (size_t)(n0 + nl) * T_STEPS;

  float cst[16];
  #pragma unroll
  for (int i = 0; i < 16; ++i) cst[i] = 0.f;

  const int wq_hi = quad >> 1;
  const int j0    = (quad & 1) * 4;

  float xv = xrow[0];

  #pragma unroll 1
  for (int t = 0; t < T_STEPS; ++t) {
    const float xn = xrow[(t + 1 <= 63) ? (t + 1) : 63];
    LSTM_STEP();
    xv = xn;
  }

  // epilogue: final h sits in scratch in B-frag order -> x1 = relu(h), fp16.
  // role 0 writes kt banks 0-1, role 1 banks 2-3.
  #pragma unroll
  for (int k = 0; k < 2; ++k) {
    const int kt = role * 2 + k;
    half8 hf = *(const half8*)&scrLane[kt * 512];
    #pragma unroll
    for (int j = 0; j < 8; ++j)
      hf[j] = (_Float16)fmaxf((float)hf[j], 0.f);
    *(half8*)&x1[(size_t)(n0 + nl) * HDIM + kt * 32 + quad * 8] = hf;
  }
}

// ---------------------------------------------------------------------------
// Y[n][j] = sum_k X[n][k] * W[j][k].  32 nodes/block, W LDS-tiled in 64-row
// chunks. Templated on input/output element type (fp16 intermediates).
template <int J, typename IT, typename OT>
__global__ __launch_bounds__(256) void gemm_xw(
    const IT* __restrict__ X, const float* __restrict__ W, OT* __restrict__ Y)
{
  __shared__ float Xs[32 * 132];
  __shared__ float Ws[64 * 132];
  const int tid = threadIdx.x;
  const int n0  = blockIdx.x * 32;
  for (int i = tid; i < 32 * 128; i += 256) {
    int nn = i >> 7, k = i & 127;
    Xs[nn * 132 + k] = (float)X[(n0 + nn) * 128 + k];
  }
  const int nl = tid >> 3;
  const int jb = tid & 7;
  for (int c0 = 0; c0 < J; c0 += 64) {
    __syncthreads();
    for (int i = tid; i < 64 * 128; i += 256) {
      int r = i >> 7, k = i & 127;
      Ws[r * 132 + k] = W[(c0 + r) * 128 + k];
    }
    __syncthreads();
    float acc[8];
    #pragma unroll
    for (int m = 0; m < 8; ++m) acc[m] = 0.f;
    for (int k0 = 0; k0 < 128; k0 += 8) {
      float xr[8];
      #pragma unroll
      for (int r = 0; r < 8; ++r) xr[r] = Xs[nl * 132 + k0 + r];
      #pragma unroll
      for (int m = 0; m < 8; ++m) {
        const float* w = &Ws[(jb + (m << 3)) * 132 + k0];
        float a = acc[m];
        #pragma unroll
        for (int r = 0; r < 8; ++r) a += xr[r] * w[r];
        acc[m] = a;
      }
    }
    #pragma unroll
    for (int m = 0; m < 8; ++m)
      Y[(n0 + nl) * J + c0 + jb + (m << 3)] = (OT)acc[m];
  }
}

// ---------------------------------------------------------------------------
__global__ void zero_kernel(float* __restrict__ deg, int* __restrict__ cnt,
                            float* __restrict__ accum)
{
  int i = blockIdx.x * 256 + threadIdx.x;
  if (i < N_NODES) { deg[i] = 0.f; cnt[i] = 0; }
  if (i < JOUT) accum[i] = 0.f;
}

__global__ void count_kernel(const int* __restrict__ ei, const float* __restrict__ ew,
                             int* __restrict__ cnt, float* __restrict__ deg)
{
  int e = blockIdx.x * 256 + threadIdx.x;
  int c = ei[N_EDGES + e];
  atomicAdd(&cnt[c], 1);
  atomicAdd(&deg[c], ew[e]);
}

// shuffle-based exclusive scan: thread t owns elements [t*20, t*20+20).
__global__ __launch_bounds__(1024) void scan_kernel(
    const int* __restrict__ cnt, int* __restrict__ rowptr, int* __restrict__ cursor,
    const float* __restrict__ deg, float* __restrict__ dinv)
{
  const int tid  = threadIdx.x;
  const int lane = tid & 63;
  const int wv   = tid >> 6;        // 16 waves
  const int base = tid * 20;
  int vals[20];
  int sum = 0;
  if (tid < 1000) {
    #pragma unroll
    for (int j = 0; j < 20; ++j) { vals[j] = sum; sum += cnt[base + j]; }
  }
  int inc = sum;
  #pragma unroll
  for (int off = 1; off < 64; off <<= 1) {
    int t = __shfl_up(inc, off);
    if (lane >= off) inc += t;
  }
  __shared__ int wtot[16];
  __shared__ int wpre[16];
  if (lane == 63) wtot[wv] = inc;
  __syncthreads();
  if (tid == 0) {
    int s = 0;
    for (int i = 0; i < 16; ++i) { wpre[i] = s; s += wtot[i]; }
    rowptr[N_NODES] = s;
  }
  __syncthreads();
  if (tid < 1000) {
    int off = wpre[wv] + (inc - sum);
    #pragma unroll
    for (int j = 0; j < 20; ++j) {
      int v = off + vals[j];
      rowptr[base + j] = v;
      cursor[base + j] = v;
    }
  }
  for (int i = tid; i < N_NODES; i += 1024)
    dinv[i] = rsqrtf(deg[i] + 1.0f);   // +1 = self-loop weight
}

__global__ void fill_kernel(const int* __restrict__ ei, const float* __restrict__ ew,
                            const float* __restrict__ dinv, int* __restrict__ cursor,
                            int* __restrict__ esrc, float* __restrict__ ewn)
{
  int e = blockIdx.x * 256 + threadIdx.x;
  int r = ei[e];
  int c = ei[N_EDGES + e];
  int p = atomicAdd(&cursor[c], 1);
  esrc[p] = r;
  ewn[p]  = ew[e] * dinv[r];   // pre-scale by dinv[row]
}

// ---------------------------------------------------------------------------
// GCN aggregation: one wave per destination node; 64-edge tiles staged in LDS,
// broadcast loop unrolled x4. y is fp16 (half2 per lane). x2 = relu(agg + b).
__global__ __launch_bounds__(256) void gcn_agg_kernel(
    const _Float16* __restrict__ y, const float* __restrict__ dinv,
    const int* __restrict__ rowptr, const int* __restrict__ esrc,
    const float* __restrict__ ewn, const float* __restrict__ gcn_b,
    float* __restrict__ x2)
{
  __shared__ float2 stg[4][64];
  const int lane = threadIdx.x & 63;
  const int wv = threadIdx.x >> 6;
  const int c = blockIdx.x * 4 + wv;
  const float dc = dinv[c];
  const half2v* y2 = (const half2v*)y;
  half2v yc = y2[c * 64 + lane];
  float ax = (float)yc[0] * dc * dc, ay = (float)yc[1] * dc * dc; // self-loop
  const int e0 = rowptr[c], e1 = rowptr[c + 1];
  for (int tb = e0; tb < e1; tb += 64) {
    const int cnt = min(64, e1 - tb);
    const int k = tb + lane;
    if (k < e1) stg[wv][lane] = make_float2(__int_as_float(esrc[k]), ewn[k] * dc);
    __builtin_amdgcn_wave_barrier();
    int i = 0;
    for (; i + 4 <= cnt; i += 4) {
      float2 p0 = stg[wv][i],     p1 = stg[wv][i + 1];
      float2 p2 = stg[wv][i + 2], p3 = stg[wv][i + 3];
      const half2v a0 = y2[(size_t)__float_as_int(p0.x) * 64 + lane];
      const half2v a1 = y2[(size_t)__float_as_int(p1.x) * 64 + lane];
      const half2v a2 = y2[(size_t)__float_as_int(p2.x) * 64 + lane];
      const half2v a3 = y2[(size_t)__float_as_int(p3.x) * 64 + lane];
      ax += (float)a0[0] * p0.y + (float)a1[0] * p1.y +
            (float)a2[0] * p2.y + (float)a3[0] * p3.y;
      ay += (float)a0[1] * p0.y + (float)a1[1] * p1.y +
            (float)a2[1] * p2.y + (float)a3[1] * p3.y;
    }
    for (; i < cnt; ++i) {
      float2 p0 = stg[wv][i];
      const half2v a0 = y2[(size_t)__float_as_int(p0.x) * 64 + lane];
      ax += (float)a0[0] * p0.y; ay += (float)a0[1] * p0.y;
    }
    __builtin_amdgcn_wave_barrier();
  }
  int j0 = lane * 2;
  x2[c * 128 + j0]     = fmaxf(ax + gcn_b[j0], 0.f);
  x2[c * 128 + j0 + 1] = fmaxf(ay + gcn_b[j0 + 1], 0.f);
}

// ---------------------------------------------------------------------------
// Per-node attention logits from fp16 xh: a_src/a_dst [N][4] (padded float4)
__global__ __launch_bounds__(256) void gat_att_kernel(
    const _Float16* __restrict__ xh, const float* __restrict__ att_src,
    const float* __restrict__ att_dst, float4* __restrict__ asrc,
    float4* __restrict__ adst)
{
  const int lane = threadIdx.x & 63;
  const int nd = blockIdx.x * 4 + (threadIdx.x >> 6);
  float s[3], d[3];
  #pragma unroll
  for (int h = 0; h < 3; ++h) {
    float xv = (float)xh[nd * JOUT + h * 64 + lane];
    s[h] = xv * att_src[h * 64 + lane];
    d[h] = xv * att_dst[h * 64 + lane];
  }
  #pragma unroll
  for (int off = 1; off < 64; off <<= 1) {
    #pragma unroll
    for (int h = 0; h < 3; ++h) {
      s[h] += __shfl_xor(s[h], off);
      d[h] += __shfl_xor(d[h], off);
    }
  }
  if (lane == 0) {
    asrc[nd] = make_float4(s[0], s[1], s[2], 0.f);
    adst[nd] = make_float4(d[0], d[1], d[2], 0.f);
  }
}

// GAT: softmax over incoming edges (incl self-loop) + weighted agg.
// One wave per node; first-tile alpha cached in regs; xh gathered in fp16.
__global__ __launch_bounds__(256) void gat_agg_kernel(
    const _Float16* __restrict__ xh, const float4* __restrict__ asrc,
    const float4* __restrict__ adst, const int* __restrict__ rowptr,
    const int* __restrict__ esrc, float* __restrict__ accum)
{
  __shared__ float4 cstg[4][64];
  const int lane = threadIdx.x & 63;
  const int wv = threadIdx.x >> 6;
  const int c = blockIdx.x * 4 + wv;
  const int e0 = rowptr[c], e1 = rowptr[c + 1];
  float4 adc = adst[c];
  float4 asc = asrc[c];
  float self0 = lrelu(asc.x + adc.x);
  float self1 = lrelu(asc.y + adc.y);
  float self2 = lrelu(asc.z + adc.z);

  const bool has = (e0 + lane < e1);
  int s_first = 0;
  float v0 = -3.0e38f, v1 = -3.0e38f, v2 = -3.0e38f;
  if (has) {
    s_first = esrc[e0 + lane];
    float4 av = asrc[s_first];
    v0 = lrelu(av.x + adc.x);
    v1 = lrelu(av.y + adc.y);
    v2 = lrelu(av.z + adc.z);
  }
  float m0 = fmaxf(self0, v0), m1 = fmaxf(self1, v1), m2 = fmaxf(self2, v2);
  for (int k = e0 + 64 + lane; k < e1; k += 64) {
    float4 av = asrc[esrc[k]];
    m0 = fmaxf(m0, lrelu(av.x + adc.x));
    m1 = fmaxf(m1, lrelu(av.y + adc.y));
    m2 = fmaxf(m2, lrelu(av.z + adc.z));
  }
  #pragma unroll
  for (int off = 1; off < 64; off <<= 1) {
    m0 = fmaxf(m0, __shfl_xor(m0, off));
    m1 = fmaxf(m1, __shfl_xor(m1, off));
    m2 = fmaxf(m2, __shfl_xor(m2, off));
  }
  float ex0 = has ? __expf(v0 - m0) : 0.f;
  float ex1 = has ? __expf(v1 - m1) : 0.f;
  float ex2 = has ? __expf(v2 - m2) : 0.f;
  float d0 = ex0, d1 = ex1, d2 = ex2;
  for (int k = e0 + 64 + lane; k < e1; k += 64) {
    float4 av = asrc[esrc[k]];
    d0 += __expf(lrelu(av.x + adc.x) - m0);
    d1 += __expf(lrelu(av.y + adc.y) - m1);
    d2 += __expf(lrelu(av.z + adc.z) - m2);
  }
  #pragma unroll
  for (int off = 1; off < 64; off <<= 1) {
    d0 += __shfl_xor(d0, off);
    d1 += __shfl_xor(d1, off);
    d2 += __shfl_xor(d2, off);
  }
  float se0 = __expf(self0 - m0), se1 = __expf(self1 - m1), se2 = __expf(self2 - m2);
  d0 += se0; d1 += se1; d2 += se2;
  float iv0 = 1.f / d0, iv1 = 1.f / d1, iv2 = 1.f / d2;

  float o0 = se0 * iv0 * (float)xh[c * JOUT + lane];
  float o1 = se1 * iv1 * (float)xh[c * JOUT + 64 + lane];
  float o2 = se2 * iv2 * (float)xh[c * JOUT + 128 + lane];

  for (int tb = e0; tb < e1; tb += 64) {
    const int cnt = min(64, e1 - tb);
    if (tb == e0) {
      if (has)
        cstg[wv][lane] = make_float4(__int_as_float(s_first),
                                     ex0 * iv0, ex1 * iv1, ex2 * iv2);
    } else {
      const int k = tb + lane;
      if (k < e1) {
        int s = esrc[k];
        float4 av = asrc[s];
        cstg[wv][lane] = make_float4(__int_as_float(s),
            __expf(lrelu(av.x + adc.x) - m0) * iv0,
            __expf(lrelu(av.y + adc.y) - m1) * iv1,
            __expf(lrelu(av.z + adc.z) - m2) * iv2);
      }
    }
    __builtin_amdgcn_wave_barrier();
    int i = 0;
    for (; i + 2 <= cnt; i += 2) {
      float4 q0 = cstg[wv][i], q1 = cstg[wv][i + 1];
      const _Float16* r0 = xh + (size_t)__float_as_int(q0.x) * JOUT;
      const _Float16* r1 = xh + (size_t)__float_as_int(q1.x) * JOUT;
      float a0 = (float)r0[lane], b0 = (float)r0[64 + lane], g0 = (float)r0[128 + lane];
      float a1 = (float)r1[lane], b1 = (float)r1[64 + lane], g1 = (float)r1[128 + lane];
      o0 += q0.y * a0 + q1.y * a1;
      o1 += q0.z * b0 + q1.z * b1;
      o2 += q0.w * g0 + q1.w * g1;
    }
    for (; i < cnt; ++i) {
      float4 q0 = cstg[wv][i];
      const _Float16* r0 = xh + (size_t)__float_as_int(q0.x) * JOUT;
      o0 += q0.y * (float)r0[lane];
      o1 += q0.z * (float)r0[64 + lane];
      o2 += q0.w * (float)r0[128 + lane];
    }
    __builtin_amdgcn_wave_barrier();
  }

  __shared__ float red[4][JOUT];
  red[wv][lane]       = o0;
  red[wv][64 + lane]  = o1;
  red[wv][128 + lane] = o2;
  __syncthreads();
  if (threadIdx.x < JOUT) {
    float sum = red[0][threadIdx.x] + red[1][threadIdx.x] +
                red[2][threadIdx.x] + red[3][threadIdx.x];
    atomicAdd(&accum[threadIdx.x], sum);
  }
}

__global__ void finalize_kernel(const float* __restrict__ accum,
                                const float* __restrict__ gat_b,
                                float* __restrict__ out)
{
  int j = threadIdx.x;
  if (j < JOUT) out[j] = accum[j] * (1.0f / N_NODES) + gat_b[j];
}

// ---------------------------------------------------------------------------
extern "C" void kernel_launch(void* const* d_in, const int* in_sizes, int n_in,
                              void* d_out, int out_size, void* d_ws, size_t ws_size,
                              hipStream_t stream)
{
  const float* xfeat = (const float*)d_in[0];
  const int*   eidx  = (const int*)d_in[1];
  const float* eattr = (const float*)d_in[2];
  const float* Wih   = (const float*)d_in[3];
  const float* Whh   = (const float*)d_in[4];
  const float* bihp  = (const float*)d_in[5];
  const float* bhhp  = (const float*)d_in[6];
  const float* gcnW  = (const float*)d_in[7];
  const float* gcnb  = (const float*)d_in[8];
  const float* gatW  = (const float*)d_in[9];
  const float* attS  = (const float*)d_in[10];
  const float* attD  = (const float*)d_in[11];
  const float* gatb  = (const float*)d_in[12];
  float* out = (float*)d_out;

  char* ws = (char*)d_ws;
  size_t off = 0;
  auto alloc = [&](size_t bytes) {
    char* p = ws + off;
    off += (bytes + 255) & ~size_t(255);
    return p;
  };
  _Float16*  x1     = (_Float16*)alloc((size_t)N_NODES * 128 * 2);
  _Float16*  y      = (_Float16*)alloc((size_t)N_NODES * 128 * 2);
  float*     x2     = (float*)alloc((size_t)N_NODES * 128 * 4);
  _Float16*  xh     = (_Float16*)alloc((size_t)N_NODES * 192 * 2);
  float4*    asrc   = (float4*)alloc((size_t)N_NODES * 16);
  float4*    adst   = (float4*)alloc((size_t)N_NODES * 16);
  float*     deg    = (float*)alloc((size_t)N_NODES * 4);
  float*     dinv   = (float*)alloc((size_t)N_NODES * 4);
  int*       cnt    = (int*)alloc((size_t)N_NODES * 4);
  int*       rowptr = (int*)alloc((size_t)(N_NODES + 1) * 4);
  int*       cursor = (int*)alloc((size_t)N_NODES * 4);
  int*       esrc   = (int*)alloc((size_t)N_EDGES * 4);
  float*     ewn    = (float*)alloc((size_t)N_EDGES * 4);
  float*     accum  = (float*)alloc(JOUT * 4);
  _Float16*  wpack  = (_Float16*)alloc(131072);

  // opt-in to >64KB dynamic LDS for the wave-pair LSTM (idempotent)
  hipFuncSetAttribute((const void*)lstm_stream_kernel,
                      hipFuncAttributeMaxDynamicSharedMemorySize, LDS_TOTAL);

  zero_kernel<<<(N_NODES + 255) / 256, 256, 0, stream>>>(deg, cnt, accum);
  pack_whh_kernel<<<32, 256, 0, stream>>>(Whh, wpack);
  lstm_stream_kernel<<<N_NODES / NBB, BTHR, LDS_TOTAL, stream>>>(
      xfeat, wpack, Wih, bihp, bhhp, x1);
  count_kernel<<<N_EDGES / 256, 256, 0, stream>>>(eidx, eattr, cnt, deg);
  scan_kernel<<<1, 1024, 0, stream>>>(cnt, rowptr, cursor, deg, dinv);
  fill_kernel<<<N_EDGES / 256, 256, 0, stream>>>(eidx, eattr, dinv, cursor, esrc, ewn);
  gemm_xw<128, _Float16, _Float16><<<N_NODES / 32, 256, 0, stream>>>(x1, gcnW, y);
  gcn_agg_kernel<<<N_NODES / 4, 256, 0, stream>>>(y, dinv, rowptr, esrc, ewn, gcnb, x2);
  gemm_xw<192, float, _Float16><<<N_NODES / 32, 256, 0, stream>>>(x2, gatW, xh);
  gat_att_kernel<<<N_NODES / 4, 256, 0, stream>>>(xh, attS, attD, asrc, adst);
  gat_agg_kernel<<<N_NODES / 4, 256, 0, stream>>>(xh, asrc, adst, rowptr, esrc, accum);
  finalize_kernel<<<1, 256, 0, stream>>>(accum, gatb, out);
}

// Round 8
// 719.965 us; speedup vs baseline: 1.2245x; 1.0689x over previous
//
#include <hip/hip_runtime.h>

// TemporalGAT: LSTM(T=64,H=128) -> ReLU -> GCNConv -> ReLU -> GATConv(3x64) -> mean
// Round 22:
// (1) LSTM lockstep fix: VALUBusy pinned at ~49% because the two per-step
//     __syncthreads sync ALL 10 waves, but the h-scratch is GROUP-private --
//     only the wave PAIR needs to sync. Replace with pair-local LDS flag
//     handshakes (epoch counters, lane-0 poll + s_sleep, threadfence for
//     ordering). The 5 groups drift out of phase -> one group's PHASE4
//     VALU/exp2 chain overlaps another's MFMA/ds phase.
// (2) MFMA GEMMs: gcnW/gatW packed to fp16 A-fragments; y = x1@W^T and
//     xh = x2@W^T via 16x16x32 f16 MFMA (32-48 MFMA/wave vs ~1150
//     LDS-read-bound VALU ops). x2 stored fp16 (r21: fp16 intermediates
//     left absmax unchanged).

#define N_NODES 20000
#define T_STEPS 64
#define N_EDGES 640000
#define HDIM    128
#define JOUT    192   // HEADS*OUT = 3*64
#define NEG_SLOPE 0.2f
#define NBW     16    // nodes per group
#define NGRP    5
#define NBB     (NBW * NGRP)   // 80 nodes per block
#define BTHR    640            // 10 waves: 5 groups x 2 roles
#define LDS_W     131072                  // packed Whh fp16
#define LDS_BW    4096                    // (bias, wih) float2[512]
#define LDS_SCR   (NGRP * 4096)           // per-group h scratch
#define LDS_FLG   256                     // pair-sync flags
#define LDS_TOTAL (LDS_W + LDS_BW + LDS_SCR + LDS_FLG)   // 155904

#define L2E  1.4426950408889634f
#define K2E  2.8853900817779268f   // 2*log2(e)

typedef _Float16 half8 __attribute__((ext_vector_type(8)));
typedef _Float16 half4v __attribute__((ext_vector_type(4)));
typedef _Float16 half2v __attribute__((ext_vector_type(2)));
typedef float floatx4 __attribute__((ext_vector_type(4)));

__device__ __forceinline__ float lrelu(float x) { return x > 0.f ? x : NEG_SLOPE * x; }

// ---------------------------------------------------------------------------
// Pre-pack Whh (fp32 [512][128]) into fp16 MFMA A-fragment order, PRE-SCALED
// into the exp2 domain (i,f,o rows x log2e; g rows x 2log2e).
__global__ void pack_whh_kernel(const float* __restrict__ Whh,
                                _Float16* __restrict__ Wpack)
{
  int i = blockIdx.x * 256 + threadIdx.x;   // 0..8191
  int tile = i >> 6, lane = i & 63;
  int nt = tile >> 2, kt = tile & 3;
  int row = nt * 16 + (lane & 15);
  int c0  = kt * 32 + (lane >> 4) * 8;
  const float sc = ((row >> 7) == 2) ? K2E : L2E;
  half8 v;
  #pragma unroll
  for (int j = 0; j < 8; ++j)
    v[j] = (_Float16)(Whh[row * 128 + c0 + j] * sc);
  *(half8*)&Wpack[(size_t)i * 8] = v;
}

// Pack a [M][128] fp32 weight into fp16 A-fragment order (M/16 x 4 tiles).
template <int M>
__global__ void pack_w_kernel(const float* __restrict__ W,
                              _Float16* __restrict__ P)
{
  int i = blockIdx.x * 256 + threadIdx.x;   // < (M/16)*4*64
  int tile = i >> 6, lane = i & 63;
  int mt = tile >> 2, kt = tile & 3;
  int row = mt * 16 + (lane & 15);
  int c0  = kt * 32 + (lane >> 4) * 8;
  half8 v;
  #pragma unroll
  for (int j = 0; j < 8; ++j)
    v[j] = (_Float16)W[row * 128 + c0 + j];
  *(half8*)&P[(size_t)i * 8] = v;
}

// ---------------------------------------------------------------------------
// LSTM building blocks (L = literal local cg index 0..3).

#define INITACC(L, acc) do {                                                  \
  _Pragma("unroll") for (int g_ = 0; g_ < 4; ++g_) {                          \
    const float4 p0_ = *(const float4*)&bwRole[g_ * 128 + (L) * 16];          \
    const float4 p1_ = *(const float4*)&bwRole[g_ * 128 + (L) * 16 + 2];      \
    acc[g_][0] = p0_.x + xv * p0_.y;                                          \
    acc[g_][1] = p0_.z + xv * p0_.w;                                          \
    acc[g_][2] = p1_.x + xv * p1_.y;                                          \
    acc[g_][3] = p1_.z + xv * p1_.w;                                          \
  }                                                                           \
} while (0)

#define LDA(buf, L, KT) do {                                                  \
  _Pragma("unroll") for (int g_ = 0; g_ < 4; ++g_)                            \
    buf[g_] = *(const half8*)&WlRole[g_ * 16384 + (L) * 2048 + (KT) * 512];   \
} while (0)

#define MFA(acc, buf, KT) do {                                                \
  _Pragma("unroll") for (int g_ = 0; g_ < 4; ++g_)                            \
    acc[g_] = __builtin_amdgcn_mfma_f32_16x16x32_f16(                         \
        buf[g_], Bf[(KT)], acc[g_], 0, 0, 0);                                 \
} while (0)

#define PHASE4(L, acc) do {                                                   \
  const int cg_ = cgb + (L);                                                  \
  half4v hpack;                                                               \
  _Pragma("unroll") for (int r_ = 0; r_ < 4; ++r_) {                          \
    const float Be = __builtin_amdgcn_exp2f(-acc[0][r_]);                     \
    const float Ae = __builtin_amdgcn_exp2f(-acc[1][r_]);                     \
    const float De = __builtin_amdgcn_exp2f(acc[2][r_]);                      \
    const float Ee = __builtin_amdgcn_exp2f(-acc[3][r_]);                     \
    const float Ap = Ae + 1.f;                                                \
    const float Bp = Be + 1.f;                                                \
    const float Dp = De + 1.f;                                                \
    const float Nn = cst[(L) * 4 + r_] * Bp * Dp + Ap * (De - 1.f);           \
    const float cv = Nn * __builtin_amdgcn_rcpf(Ap * Bp * Dp);                \
    cst[(L) * 4 + r_] = cv;                                                   \
    const float cvc = fminf(fmaxf(cv, -10.f), 10.f);                          \
    const float Fe = __builtin_amdgcn_exp2f(K2E * cvc);                       \
    hpack[r_] = (_Float16)((Fe - 1.f) *                                       \
                __builtin_amdgcn_rcpf((Ee + 1.f) * (Fe + 1.f)));              \
  }                                                                           \
  const int lp_ = nl + 16 * (2 * (cg_ & 1) + wq_hi);                          \
  *(half4v*)&myscr[(cg_ >> 1) * 512 + lp_ * 8 + j0] = hpack;                  \
} while (0)

#define SB __builtin_amdgcn_sched_barrier(0)

// Pair-local sync: SIGNAL publishes epoch after a fence; WAITGE spins
// (lane 0) until the partner reaches the epoch, then fences.
#define SIGNAL(arr, val) do {                                                 \
  __threadfence_block();                                                      \
  if (ln == 0) arr[wv] = (val);                                               \
} while (0)
#define WAITGE(arr, val) do {                                                 \
  if (ln == 0) { while (arr[pw] < (val)) __builtin_amdgcn_s_sleep(1); }       \
  __builtin_amdgcn_wave_barrier();                                            \
  __threadfence_block();                                                      \
} while (0)

// One LSTM step for one role (4 cg groups), depth-2 acc pipeline, pair-local
// sync. Epochs: wait partner's writes of step t-1 (flW >= t), read Bf, signal
// reads (flR = t+1); before the first h-write wait partner's reads
// (flR >= t+1); after last write signal flW = t+1.
#define LSTM_STEP(t) do {                                                     \
  WAITGE(flW, (t));                                                           \
  half8 Bf[4];                                                                \
  _Pragma("unroll") for (int kt_ = 0; kt_ < 4; ++kt_)                         \
    Bf[kt_] = *(const half8*)&scrLane[kt_ * 512];                             \
  SIGNAL(flR, (t) + 1);                                                       \
  floatx4 accA[4], accB[4];                                                   \
  half8 Aa[4], Ab[4];                                                         \
  /* body 0 */                                                                \
  INITACC(0, accA);                                                           \
  LDA(Aa, 0, 0); LDA(Ab, 0, 1);                                               \
  MFA(accA, Aa, 0); LDA(Aa, 0, 2);                                            \
  MFA(accA, Ab, 1); LDA(Ab, 0, 3);                                            \
  MFA(accA, Aa, 2); MFA(accA, Ab, 3);                                         \
  /* body 1 */                                                                \
  INITACC(1, accB); LDA(Aa, 1, 0); LDA(Ab, 1, 1);                             \
  WAITGE(flR, (t) + 1);                                                       \
  SB; PHASE4(0, accA);                                                        \
  MFA(accB, Aa, 0); LDA(Aa, 1, 2);                                            \
  MFA(accB, Ab, 1); LDA(Ab, 1, 3);                                            \
  MFA(accB, Aa, 2); MFA(accB, Ab, 3);                                         \
  /* body 2 */                                                                \
  INITACC(2, accA); LDA(Aa, 2, 0); LDA(Ab, 2, 1);                             \
  SB; PHASE4(1, accB);                                                        \
  MFA(accA, Aa, 0); LDA(Aa, 2, 2);                                            \
  MFA(accA, Ab, 1); LDA(Ab, 2, 3);                                            \
  MFA(accA, Aa, 2); MFA(accA, Ab, 3);                                         \
  /* body 3 */                                                                \
  INITACC(3, accB); LDA(Aa, 3, 0); LDA(Ab, 3, 1);                             \
  SB; PHASE4(2, accA);                                                        \
  MFA(accB, Aa, 0); LDA(Aa, 3, 2);                                            \
  MFA(accB, Ab, 1); LDA(Ab, 3, 3);                                            \
  MFA(accB, Aa, 2); MFA(accB, Ab, 3);                                         \
  PHASE4(3, accB);                                                            \
  SIGNAL(flW, (t) + 1);                                                       \
} while (0)

// ---------------------------------------------------------------------------
// Wave-pair LSTM. Block = 640 threads (10 waves), 5 groups x 16 nodes.
// Group g's pair: wave 2g (role 0, cg0-3) + wave 2g+1 (role 1, cg4-7).
// No block-wide barriers in the t-loop: pair-local flag sync only.
__global__ __attribute__((amdgpu_flat_work_group_size(BTHR, BTHR),
                          amdgpu_waves_per_eu(3, 3)))
void lstm_stream_kernel(
    const float* __restrict__ xfeat, const _Float16* __restrict__ Wpack,
    const float* __restrict__ Wih, const float* __restrict__ bih,
    const float* __restrict__ bhh, _Float16* __restrict__ x1)
{
  extern __shared__ char dynlds[];
  _Float16* Wl  = (_Float16*)dynlds;                    // [128 tiles][64 lanes][8]
  float2*   bw  = (float2*)(dynlds + LDS_W);            // [512] (bias, wih) pre-scaled
  _Float16* scr = (_Float16*)(dynlds + LDS_W + LDS_BW); // [5][2048]
  volatile int* flR = (volatile int*)(dynlds + LDS_W + LDS_BW + LDS_SCR);
  volatile int* flW = flR + 16;

  const int tid  = threadIdx.x;   // 0..639
  const int wv   = tid >> 6;      // wave 0..9
  const int pw   = wv ^ 1;        // partner wave
  const int grp  = wv >> 1;       // node group 0..4
  const int role = wv & 1;        // 0: cg0-3, 1: cg4-7
  const int cgb  = role * 4;
  const int ln   = tid & 63;
  const int nl   = ln & 15;       // node within group
  const int quad = ln >> 4;
  const int n0   = blockIdx.x * NBB + grp * NBW;

  // stage packed Whh -> LDS (coalesced float4)
  {
    const float4* src = (const float4*)Wpack;
    float4* dst = (float4*)Wl;
    for (int i = tid; i < LDS_W / 16; i += BTHR) dst[i] = src[i];
  }
  for (int i = tid; i < 512; i += BTHR) {
    const float sc = ((i >> 7) == 2) ? K2E : L2E;
    bw[i] = make_float2((bih[i] + bhh[i]) * sc, Wih[i] * sc);
  }
  {
    float4* z = (float4*)scr;
    for (int i = tid; i < LDS_SCR / 16; i += BTHR)
      z[i] = make_float4(0.f, 0.f, 0.f, 0.f);
  }
  if (tid < 32) { flR[tid] = 0; flW[tid] = 0; }
  __syncthreads();   // staging barrier (the only block-wide one)

  _Float16* myscr = scr + grp * 2048;
  const _Float16* WlRole  = Wl + (size_t)cgb * 2048 + (size_t)ln * 8;
  const float2*   bwRole  = bw + cgb * 16 + quad * 4;
  const _Float16* scrLane = myscr + (size_t)ln * 8;
  const float* xrow = xfeat + (size_t)(n0 + nl) * T_STEPS;

  float cst[16];
  #pragma unroll
  for (int i = 0; i < 16; ++i) cst[i] = 0.f;

  const int wq_hi = quad >> 1;
  const int j0    = (quad & 1) * 4;

  float xv = xrow[0];

  #pragma unroll 1
  for (int t = 0; t < T_STEPS; ++t) {
    const float xn = xrow[(t + 1 <= 63) ? (t + 1) : 63];
    LSTM_STEP(t);
    xv = xn;
  }

  // epilogue: each role reads only its own written banks -> no final sync.
  #pragma unroll
  for (int k = 0; k < 2; ++k) {
    const int kt = role * 2 + k;
    half8 hf = *(const half8*)&scrLane[kt * 512];
    #pragma unroll
    for (int j = 0; j < 8; ++j)
      hf[j] = (_Float16)fmaxf((float)hf[j], 0.f);
    *(half8*)&x1[(size_t)(n0 + nl) * HDIM + kt * 32 + quad * 8] = hf;
  }
}

// ---------------------------------------------------------------------------
// MFMA GEMM: Y[n][j] = sum_k X[n][k] W[j][k], X fp16 [N][128], W packed fp16
// A-frags, Y fp16. 320 threads = 5 waves; wave handles 16 nodes x full J.
template <int J>
__global__ __launch_bounds__(320) void gemm_mfma(
    const _Float16* __restrict__ X, const _Float16* __restrict__ P,
    _Float16* __restrict__ Y)
{
  const int ln = threadIdx.x & 63;
  const int wv = threadIdx.x >> 6;   // 0..4
  const int node = blockIdx.x * 80 + wv * 16 + (ln & 15);
  const int ko = (ln >> 4) * 8;
  half8 Bf[4];
  #pragma unroll
  for (int kt = 0; kt < 4; ++kt)
    Bf[kt] = *(const half8*)&X[(size_t)node * 128 + kt * 32 + ko];
  #pragma unroll
  for (int m = 0; m < J / 16; ++m) {
    floatx4 acc = {0.f, 0.f, 0.f, 0.f};
    #pragma unroll
    for (int kt = 0; kt < 4; ++kt) {
      const half8 Af = *(const half8*)&P[(size_t)((m * 4 + kt) * 64 + ln) * 8];
      acc = __builtin_amdgcn_mfma_f32_16x16x32_f16(Af, Bf[kt], acc, 0, 0, 0);
    }
    half4v o;
    #pragma unroll
    for (int j = 0; j < 4; ++j) o[j] = (_Float16)acc[j];
    // C layout: col = ln&15 (node), row = (ln>>4)*4 + j (J index)
    *(half4v*)&Y[(size_t)node * J + m * 16 + (ln >> 4) * 4] = o;
  }
}

// ---------------------------------------------------------------------------
__global__ void zero_kernel(float* __restrict__ deg, int* __restrict__ cnt,
                            float* __restrict__ accum)
{
  int i = blockIdx.x * 256 + threadIdx.x;
  if (i < N_NODES) { deg[i] = 0.f; cnt[i] = 0; }
  if (i < JOUT) accum[i] = 0.f;
}

__global__ void count_kernel(const int* __restrict__ ei, const float* __restrict__ ew,
                             int* __restrict__ cnt, float* __restrict__ deg)
{
  int e = blockIdx.x * 256 + threadIdx.x;
  int c = ei[N_EDGES + e];
  atomicAdd(&cnt[c], 1);
  atomicAdd(&deg[c], ew[e]);
}

// shuffle-based exclusive scan: thread t owns elements [t*20, t*20+20).
__global__ __launch_bounds__(1024) void scan_kernel(
    const int* __restrict__ cnt, int* __restrict__ rowptr, int* __restrict__ cursor,
    const float* __restrict__ deg, float* __restrict__ dinv)
{
  const int tid  = threadIdx.x;
  const int lane = tid & 63;
  const int wv   = tid >> 6;        // 16 waves
  const int base = tid * 20;
  int vals[20];
  int sum = 0;
  if (tid < 1000) {
    #pragma unroll
    for (int j = 0; j < 20; ++j) { vals[j] = sum; sum += cnt[base + j]; }
  }
  int inc = sum;
  #pragma unroll
  for (int off = 1; off < 64; off <<= 1) {
    int t = __shfl_up(inc, off);
    if (lane >= off) inc += t;
  }
  __shared__ int wtot[16];
  __shared__ int wpre[16];
  if (lane == 63) wtot[wv] = inc;
  __syncthreads();
  if (tid == 0) {
    int s = 0;
    for (int i = 0; i < 16; ++i) { wpre[i] = s; s += wtot[i]; }
    rowptr[N_NODES] = s;
  }
  __syncthreads();
  if (tid < 1000) {
    int off = wpre[wv] + (inc - sum);
    #pragma unroll
    for (int j = 0; j < 20; ++j) {
      int v = off + vals[j];
      rowptr[base + j] = v;
      cursor[base + j] = v;
    }
  }
  for (int i = tid; i < N_NODES; i += 1024)
    dinv[i] = rsqrtf(deg[i] + 1.0f);   // +1 = self-loop weight
}

__global__ void fill_kernel(const int* __restrict__ ei, const float* __restrict__ ew,
                            const float* __restrict__ dinv, int* __restrict__ cursor,
                            int* __restrict__ esrc, float* __restrict__ ewn)
{
  int e = blockIdx.x * 256 + threadIdx.x;
  int r = ei[e];
  int c = ei[N_EDGES + e];
  int p = atomicAdd(&cursor[c], 1);
  esrc[p] = r;
  ewn[p]  = ew[e] * dinv[r];   // pre-scale by dinv[row]
}

// ---------------------------------------------------------------------------
// GCN aggregation: one wave per destination node; y fp16; x2 fp16 out.
__global__ __launch_bounds__(256) void gcn_agg_kernel(
    const _Float16* __restrict__ y, const float* __restrict__ dinv,
    const int* __restrict__ rowptr, const int* __restrict__ esrc,
    const float* __restrict__ ewn, const float* __restrict__ gcn_b,
    _Float16* __restrict__ x2)
{
  __shared__ float2 stg[4][64];
  const int lane = threadIdx.x & 63;
  const int wv = threadIdx.x >> 6;
  const int c = blockIdx.x * 4 + wv;
  const float dc = dinv[c];
  const half2v* y2 = (const half2v*)y;
  half2v yc = y2[c * 64 + lane];
  float ax = (float)yc[0] * dc * dc, ay = (float)yc[1] * dc * dc; // self-loop
  const int e0 = rowptr[c], e1 = rowptr[c + 1];
  for (int tb = e0; tb < e1; tb += 64) {
    const int cnt = min(64, e1 - tb);
    const int k = tb + lane;
    if (k < e1) stg[wv][lane] = make_float2(__int_as_float(esrc[k]), ewn[k] * dc);
    __builtin_amdgcn_wave_barrier();
    int i = 0;
    for (; i + 4 <= cnt; i += 4) {
      float2 p0 = stg[wv][i],     p1 = stg[wv][i + 1];
      float2 p2 = stg[wv][i + 2], p3 = stg[wv][i + 3];
      const half2v a0 = y2[(size_t)__float_as_int(p0.x) * 64 + lane];
      const half2v a1 = y2[(size_t)__float_as_int(p1.x) * 64 + lane];
      const half2v a2 = y2[(size_t)__float_as_int(p2.x) * 64 + lane];
      const half2v a3 = y2[(size_t)__float_as_int(p3.x) * 64 + lane];
      ax += (float)a0[0] * p0.y + (float)a1[0] * p1.y +
            (float)a2[0] * p2.y + (float)a3[0] * p3.y;
      ay += (float)a0[1] * p0.y + (float)a1[1] * p1.y +
            (float)a2[1] * p2.y + (float)a3[1] * p3.y;
    }
    for (; i < cnt; ++i) {
      float2 p0 = stg[wv][i];
      const half2v a0 = y2[(size_t)__float_as_int(p0.x) * 64 + lane];
      ax += (float)a0[0] * p0.y; ay += (float)a0[1] * p0.y;
    }
    __builtin_amdgcn_wave_barrier();
  }
  int j0 = lane * 2;
  half2v o;
  o[0] = (_Float16)fmaxf(ax + gcn_b[j0], 0.f);
  o[1] = (_Float16)fmaxf(ay + gcn_b[j0 + 1], 0.f);
  *(half2v*)&x2[c * 128 + j0] = o;
}

// ---------------------------------------------------------------------------
// Per-node attention logits from fp16 xh: a_src/a_dst [N][4] (padded float4)
__global__ __launch_bounds__(256) void gat_att_kernel(
    const _Float16* __restrict__ xh, const float* __restrict__ att_src,
    const float* __restrict__ att_dst, float4* __restrict__ asrc,
    float4* __restrict__ adst)
{
  const int lane = threadIdx.x & 63;
  const int nd = blockIdx.x * 4 + (threadIdx.x >> 6);
  float s[3], d[3];
  #pragma unroll
  for (int h = 0; h < 3; ++h) {
    float xv = (float)xh[nd * JOUT + h * 64 + lane];
    s[h] = xv * att_src[h * 64 + lane];
    d[h] = xv * att_dst[h * 64 + lane];
  }
  #pragma unroll
  for (int off = 1; off < 64; off <<= 1) {
    #pragma unroll
    for (int h = 0; h < 3; ++h) {
      s[h] += __shfl_xor(s[h], off);
      d[h] += __shfl_xor(d[h], off);
    }
  }
  if (lane == 0) {
    asrc[nd] = make_float4(s[0], s[1], s[2], 0.f);
    adst[nd] = make_float4(d[0], d[1], d[2], 0.f);
  }
}

// GAT: softmax over incoming edges (incl self-loop) + weighted agg.
__global__ __launch_bounds__(256) void gat_agg_kernel(
    const _Float16* __restrict__ xh, const float4* __restrict__ asrc,
    const float4* __restrict__ adst, const int* __restrict__ rowptr,
    const int* __restrict__ esrc, float* __restrict__ accum)
{
  __shared__ float4 cstg[4][64];
  const int lane = threadIdx.x & 63;
  const int wv = threadIdx.x >> 6;
  const int c = blockIdx.x * 4 + wv;
  const int e0 = rowptr[c], e1 = rowptr[c + 1];
  float4 adc = adst[c];
  float4 asc = asrc[c];
  float self0 = lrelu(asc.x + adc.x);
  float self1 = lrelu(asc.y + adc.y);
  float self2 = lrelu(asc.z + adc.z);

  const bool has = (e0 + lane < e1);
  int s_first = 0;
  float v0 = -3.0e38f, v1 = -3.0e38f, v2 = -3.0e38f;
  if (has) {
    s_first = esrc[e0 + lane];
    float4 av = asrc[s_first];
    v0 = lrelu(av.x + adc.x);
    v1 = lrelu(av.y + adc.y);
    v2 = lrelu(av.z + adc.z);
  }
  float m0 = fmaxf(self0, v0), m1 = fmaxf(self1, v1), m2 = fmaxf(self2, v2);
  for (int k = e0 + 64 + lane; k < e1; k += 64) {
    float4 av = asrc[esrc[k]];
    m0 = fmaxf(m0, lrelu(av.x + adc.x));
    m1 = fmaxf(m1, lrelu(av.y + adc.y));
    m2 = fmaxf(m2, lrelu(av.z + adc.z));
  }
  #pragma unroll
  for (int off = 1; off < 64; off <<= 1) {
    m0 = fmaxf(m0, __shfl_xor(m0, off));
    m1 = fmaxf(m1, __shfl_xor(m1, off));
    m2 = fmaxf(m2, __shfl_xor(m2, off));
  }
  float ex0 = has ? __expf(v0 - m0) : 0.f;
  float ex1 = has ? __expf(v1 - m1) : 0.f;
  float ex2 = has ? __expf(v2 - m2) : 0.f;
  float d0 = ex0, d1 = ex1, d2 = ex2;
  for (int k = e0 + 64 + lane; k < e1; k += 64) {
    float4 av = asrc[esrc[k]];
    d0 += __expf(lrelu(av.x + adc.x) - m0);
    d1 += __expf(lrelu(av.y + adc.y) - m1);
    d2 += __expf(lrelu(av.z + adc.z) - m2);
  }
  #pragma unroll
  for (int off = 1; off < 64; off <<= 1) {
    d0 += __shfl_xor(d0, off);
    d1 += __shfl_xor(d1, off);
    d2 += __shfl_xor(d2, off);
  }
  float se0 = __expf(self0 - m0), se1 = __expf(self1 - m1), se2 = __expf(self2 - m2);
  d0 += se0; d1 += se1; d2 += se2;
  float iv0 = 1.f / d0, iv1 = 1.f / d1, iv2 = 1.f / d2;

  float o0 = se0 * iv0 * (float)xh[c * JOUT + lane];
  float o1 = se1 * iv1 * (float)xh[c * JOUT + 64 + lane];
  float o2 = se2 * iv2 * (float)xh[c * JOUT + 128 + lane];

  for (int tb = e0; tb < e1; tb += 64) {
    const int cnt = min(64, e1 - tb);
    if (tb == e0) {
      if (has)
        cstg[wv][lane] = make_float4(__int_as_float(s_first),
                                     ex0 * iv0, ex1 * iv1, ex2 * iv2);
    } else {
      const int k = tb + lane;
      if (k < e1) {
        int s = esrc[k];
        float4 av = asrc[s];
        cstg[wv][lane] = make_float4(__int_as_float(s),
            __expf(lrelu(av.x + adc.x) - m0) * iv0,
            __expf(lrelu(av.y + adc.y) - m1) * iv1,
            __expf(lrelu(av.z + adc.z) - m2) * iv2);
      }
    }
    __builtin_amdgcn_wave_barrier();
    int i = 0;
    for (; i + 2 <= cnt; i += 2) {
      float4 q0 = cstg[wv][i], q1 = cstg[wv][i + 1];
      const _Float16* r0 = xh + (size_t)__float_as_int(q0.x) * JOUT;
      const _Float16* r1 = xh + (size_t)__float_as_int(q1.x) * JOUT;
      float a0 = (float)r0[lane], b0 = (float)r0[64 + lane], g0 = (float)r0[128 + lane];
      float a1 = (float)r1[lane], b1 = (float)r1[64 + lane], g1 = (float)r1[128 + lane];
      o0 += q0.y * a0 + q1.y * a1;
      o1 += q0.z * b0 + q1.z * b1;
      o2 += q0.w * g0 + q1.w * g1;
    }
    for (; i < cnt; ++i) {
      float4 q0 = cstg[wv][i];
      const _Float16* r0 = xh + (size_t)__float_as_int(q0.x) * JOUT;
      o0 += q0.y * (float)r0[lane];
      o1 += q0.z * (float)r0[64 + lane];
      o2 += q0.w * (float)r0[128 + lane];
    }
    __builtin_amdgcn_wave_barrier();
  }

  __shared__ float red[4][JOUT];
  red[wv][lane]       = o0;
  red[wv][64 + lane]  = o1;
  red[wv][128 + lane] = o2;
  __syncthreads();
  if (threadIdx.x < JOUT) {
    float sum = red[0][threadIdx.x] + red[1][threadIdx.x] +
                red[2][threadIdx.x] + red[3][threadIdx.x];
    atomicAdd(&accum[threadIdx.x], sum);
  }
}

__global__ void finalize_kernel(const float* __restrict__ accum,
                                const float* __restrict__ gat_b,
                                float* __restrict__ out)
{
  int j = threadIdx.x;
  if (j < JOUT) out[j] = accum[j] * (1.0f / N_NODES) + gat_b[j];
}

// ---------------------------------------------------------------------------
extern "C" void kernel_launch(void* const* d_in, const int* in_sizes, int n_in,
                              void* d_out, int out_size, void* d_ws, size_t ws_size,
                              hipStream_t stream)
{
  const float* xfeat = (const float*)d_in[0];
  const int*   eidx  = (const int*)d_in[1];
  const float* eattr = (const float*)d_in[2];
  const float* Wih   = (const float*)d_in[3];
  const float* Whh   = (const float*)d_in[4];
  const float* bihp  = (const float*)d_in[5];
  const float* bhhp  = (const float*)d_in[6];
  const float* gcnW  = (const float*)d_in[7];
  const float* gcnb  = (const float*)d_in[8];
  const float* gatW  = (const float*)d_in[9];
  const float* attS  = (const float*)d_in[10];
  const float* attD  = (const float*)d_in[11];
  const float* gatb  = (const float*)d_in[12];
  float* out = (float*)d_out;

  char* ws = (char*)d_ws;
  size_t off = 0;
  auto alloc = [&](size_t bytes) {
    char* p = ws + off;
    off += (bytes + 255) & ~size_t(255);
    return p;
  };
  _Float16*  x1     = (_Float16*)alloc((size_t)N_NODES * 128 * 2);
  _Float16*  y      = (_Float16*)alloc((size_t)N_NODES * 128 * 2);
  _Float16*  x2     = (_Float16*)alloc((size_t)N_NODES * 128 * 2);
  _Float16*  xh     = (_Float16*)alloc((size_t)N_NODES * 192 * 2);
  float4*    asrc   = (float4*)alloc((size_t)N_NODES * 16);
  float4*    adst   = (float4*)alloc((size_t)N_NODES * 16);
  float*     deg    = (float*)alloc((size_t)N_NODES * 4);
  float*     dinv   = (float*)alloc((size_t)N_NODES * 4);
  int*       cnt    = (int*)alloc((size_t)N_NODES * 4);
  int*       rowptr = (int*)alloc((size_t)(N_NODES + 1) * 4);
  int*       cursor = (int*)alloc((size_t)N_NODES * 4);
  int*       esrc   = (int*)alloc((size_t)N_EDGES * 4);
  float*     ewn    = (float*)alloc((size_t)N_EDGES * 4);
  float*     accum  = (float*)alloc(JOUT * 4);
  _Float16*  wpack  = (_Float16*)alloc(131072);
  _Float16*  wpackG = (_Float16*)alloc((size_t)128 * 128 * 2);
  _Float16*  wpackA = (_Float16*)alloc((size_t)192 * 128 * 2);

  // opt-in to >64KB dynamic LDS for the wave-pair LSTM (idempotent)
  hipFuncSetAttribute((const void*)lstm_stream_kernel,
                      hipFuncAttributeMaxDynamicSharedMemorySize, LDS_TOTAL);

  zero_kernel<<<(N_NODES + 255) / 256, 256, 0, stream>>>(deg, cnt, accum);
  pack_whh_kernel<<<32, 256, 0, stream>>>(Whh, wpack);
  pack_w_kernel<128><<<8, 256, 0, stream>>>(gcnW, wpackG);
  pack_w_kernel<192><<<12, 256, 0, stream>>>(gatW, wpackA);
  lstm_stream_kernel<<<N_NODES / NBB, BTHR, LDS_TOTAL, stream>>>(
      xfeat, wpack, Wih, bihp, bhhp, x1);
  count_kernel<<<N_EDGES / 256, 256, 0, stream>>>(eidx, eattr, cnt, deg);
  scan_kernel<<<1, 1024, 0, stream>>>(cnt, rowptr, cursor, deg, dinv);
  fill_kernel<<<N_EDGES / 256, 256, 0, stream>>>(eidx, eattr, dinv, cursor, esrc, ewn);
  gemm_mfma<128><<<N_NODES / 80, 320, 0, stream>>>(x1, wpackG, y);
  gcn_agg_kernel<<<N_NODES / 4, 256, 0, stream>>>(y, dinv, rowptr, esrc, ewn, gcnb, x2);
  gemm_mfma<192><<<N_NODES / 80, 320, 0, stream>>>(x2, wpackA, xh);
  gat_att_kernel<<<N_NODES / 4, 256, 0, stream>>>(xh, attS, attD, asrc, adst);
  gat_agg_kernel<<<N_NODES / 4, 256, 0, stream>>>(xh, asrc, adst, rowptr, esrc, accum);
  finalize_kernel<<<1, 256, 0, stream>>>(accum, gatb, out);
}